// Round 6
// baseline (451.115 us; speedup 1.0000x reference)
//
#include <hip/hip_runtime.h>
#include <stdint.h>

// CrossAttn: B=2, Nr=Np=8192, C=256, K=8. ALL I/O float32.
// R16: k_knn hot loop -> register broadcast via v_readlane; LDS removed from
// the inner loop. R15 evidence: static ~22 instr/cand but measured ~90
// (155us, VALUBusy 107) -- suspects: per-cand ds_read_b128 broadcast +
// lgkmcnt stalls at 4.4 waves/SIMD + divergent finalize (461K bank confl).
// Now: each lane preloads one cand float4 per 64-block from L2 (coalesced);
// hot loop broadcasts cand t via 4x __builtin_amdgcn_readlane into SGPRs
// (free VALU operands) -- zero LDS / zero waits / zero conflicts in loop.
// Chain/tau/mask semantics identical to R15 (superset proof unchanged =>
// part[] bit-identical). Cands mirrored to sref once (4 ds_write_b128) only
// for the divergent finalize walk (unchanged). Masks live 1 word at a time
// (finalize per 32-half, ascending j kept). LDS 20->16KB; 8192 waves = 8/SIMD.
// Everything else unchanged from R15 (passing, 442us; k_knn 155us).
// Scratch: NO d_ws. All inside d_out dead ref-half regions:
//   g 8MB [0,8M); ref4 [8M,..); idx [8.25M,..); Aw [8.75M,..); bbig [9M,..);
//   part u16 8MB [32M,40M).
// k_gemm writes pred halves [16M,32M)+[48M,64M); k_zero zeroes ref halves LAST.

#define NRr 8192
#define NPp 8192
#define NC  256
#define NK  8
#define NCH   32     // ref chunks
#define CHUNK 256    // refs per chunk

typedef short bf16x8 __attribute__((ext_vector_type(8)));
typedef float f32x4  __attribute__((ext_vector_type(4)));

__device__ __forceinline__ uint16_t f2bf(float f) {
  uint32_t u = __float_as_uint(f);
  return (uint16_t)((u + 0x7fffu + ((u >> 16) & 1u)) >> 16);
}

// Exact np-f32 d2: rounded products, sequential adds, (sp+sr) - (dot+dot).
// Used by k_knn (all passes) and k_merge so recomputation is bitwise identical.
__device__ __forceinline__ float d2f(float px, float py, float pz, float sp, float4 r) {
  float m0 = __fmul_rn(px, r.x), m1 = __fmul_rn(py, r.y), m2 = __fmul_rn(pz, r.z);
  float dot = __fadd_rn(__fadd_rn(m0, m1), m2);
  return __fsub_rn(__fadd_rn(sp, r.w), __fadd_rn(dot, dot));
}

// ---------------- prep: ref coords + |r|^2 (literal np rounding) ------------
__global__ __launch_bounds__(64) void k_prep(const float* __restrict__ xyz_ref,
                                             float4* __restrict__ ref4) {
  int i = blockIdx.x * 64 + threadIdx.x;       // 0 .. 2*NR-1 (256 blocks x 64)
  if (i >= 2 * NRr) return;
  float x = xyz_ref[i*3+0];
  float y = xyz_ref[i*3+1];
  float z = xyz_ref[i*3+2];
  float n = __fadd_rn(__fadd_rn(__fmul_rn(x,x), __fmul_rn(y,y)), __fmul_rn(z,z));
  ref4[i] = make_float4(x, y, z, n);
}

// sorted-8 insert, strict < on d2 (scan order ascending idx => lex-stable)
__device__ __forceinline__ void insert8(float d2, int j, float (&dist)[8], int (&id)[8]) {
  if (d2 < dist[7]) {
    #pragma unroll
    for (int k = 7; k >= 1; --k) {
      bool sh = d2 < dist[k-1];
      bool pl = d2 < dist[k];
      float nd = sh ? dist[k-1] : (pl ? d2 : dist[k]);
      int   ni = sh ? id[k-1]   : (pl ? j  : id[k]);
      dist[k] = nd; id[k] = ni;
    }
    if (d2 < dist[0]) { dist[0] = d2; id[0] = j; }
  }
}

// broadcast lane L's candidate float4 (wave-uniform L) into all lanes
__device__ __forceinline__ float4 bcast4(uint32_t cx, uint32_t cy,
                                         uint32_t cz, uint32_t cw, int L) {
  return make_float4(__uint_as_float(__builtin_amdgcn_readlane(cx, L)),
                     __uint_as_float(__builtin_amdgcn_readlane(cy, L)),
                     __uint_as_float(__builtin_amdgcn_readlane(cz, L)),
                     __uint_as_float(__builtin_amdgcn_readlane(cw, L)));
}

// one 64-candidate block: readlane broadcast, dual 4-chains, per-half mask +
// immediate finalize (ascending j overall: bq asc, half asc, ctz asc)
__device__ __forceinline__ void kblock(float4 rc, int bq,
    float px, float py, float pz, float sp,
    float &a0, float &a1, float &a2, float &a3,
    float &g0, float &g1, float &g2, float &g3,
    float (&dist)[8], int (&id)[8], const float4* srefw) {
  uint32_t cx = __float_as_uint(rc.x), cy = __float_as_uint(rc.y);
  uint32_t cz = __float_as_uint(rc.z), cw = __float_as_uint(rc.w);
  #pragma unroll
  for (int half = 0; half < 2; ++half) {
    uint32_t mm = 0;
    #pragma unroll 4
    for (int t = 0; t < 32; t += 2) {
      int L0 = half*32 + t;
      float4 r0 = bcast4(cx, cy, cz, cw, L0);
      float4 r1 = bcast4(cx, cy, cz, cw, L0 + 1);
      float d0 = d2f(px, py, pz, sp, r0);
      float d1 = d2f(px, py, pz, sp, r1);
      // chain A <- even candidate (reads pre-update lower slots: top-down)
      a3 = fminf(fmaxf(d0, a2), a3);
      a2 = fminf(fmaxf(d0, a1), a2);
      a1 = fminf(fmaxf(d0, a0), a1);
      a0 = fminf(d0, a0);
      // chain G <- odd candidate
      g3 = fminf(fmaxf(d1, g2), g3);
      g2 = fminf(fmaxf(d1, g1), g2);
      g1 = fminf(fmaxf(d1, g0), g1);
      g0 = fminf(d1, g0);
      float tau = fmaxf(a3, g3);               // >= running 8th >= final T8
      mm |= (uint32_t)(d0 <= tau) << t;
      mm |= (uint32_t)(d1 <= tau) << (t + 1);
    }
    // finalize this half's survivors (ascending j, strict <)
    int jb = bq*64 + half*32;
    while (mm) {
      int bit = __builtin_ctz(mm); mm &= mm - 1;
      int j = jb + bit;
      float dd = d2f(px, py, pz, sp, srefw[j]);
      insert8(dd, j, dist, id);
    }
  }
}

// ---- brute-force KNN: 4 independent single-wave bodies per 256-thr block ---
// wave-task = blockIdx*4 + wave; ch = task & 31; point-group = task >> 5.
// Each wave stages its OWN LDS segment and never reads another wave's:
// no barrier, no cross-wave coupling.
__global__ __launch_bounds__(256, 8) void k_knn(const float* __restrict__ xyz_pred,
                                                const float4* __restrict__ ref4,
                                                uint16_t* __restrict__ part) {
  __shared__ __align__(16) float4 sref[4][CHUNK];   // 16 KB (finalize only)
  int wave = threadIdx.x >> 6;
  int lane = threadIdx.x & 63;
  int task = blockIdx.x * 4 + wave;            // 0..8191
  int ch   = task & (NCH - 1);                 // 0..31
  int P    = (task >> 5) * 64 + lane;          // global point 0..16383
  int b    = P >> 13;

  float px = xyz_pred[P*3+0];
  float py = xyz_pred[P*3+1];
  float pz = xyz_pred[P*3+2];
  float sp = __fadd_rn(__fadd_rn(__fmul_rn(px,px), __fmul_rn(py,py)), __fmul_rn(pz,pz));

  const float4* refbase = ref4 + (size_t)b * NRr;
  int rbase = ch * CHUNK;

  // each lane owns candidate (bq*64 + lane); mirror to LDS for finalize reads
  float4 rc0 = refbase[rbase +   0 + lane];
  float4 rc1 = refbase[rbase +  64 + lane];
  float4 rc2 = refbase[rbase + 128 + lane];
  float4 rc3 = refbase[rbase + 192 + lane];
  sref[wave][  0 + lane] = rc0;
  sref[wave][ 64 + lane] = rc1;
  sref[wave][128 + lane] = rc2;
  sref[wave][192 + lane] = rc3;
  // no __syncthreads: in-wave ds_write -> ds_read ordering via lgkmcnt

  float a0 = 3.4e38f, a1 = 3.4e38f, a2 = 3.4e38f, a3 = 3.4e38f;
  float g0 = 3.4e38f, g1 = 3.4e38f, g2 = 3.4e38f, g3 = 3.4e38f;
  float dist[8]; int id[8];
  #pragma unroll
  for (int k = 0; k < 8; ++k) { dist[k] = 3.4e38f; id[k] = 0; }

  const float4* srefw = &sref[wave][0];
  kblock(rc0, 0, px, py, pz, sp, a0, a1, a2, a3, g0, g1, g2, g3, dist, id, srefw);
  kblock(rc1, 1, px, py, pz, sp, a0, a1, a2, a3, g0, g1, g2, g3, dist, id, srefw);
  kblock(rc2, 2, px, py, pz, sp, a0, a1, a2, a3, g0, g1, g2, g3, dist, id, srefw);
  kblock(rc3, 3, px, py, pz, sp, a0, a1, a2, a3, g0, g1, g2, g3, dist, id, srefw);

  uint16_t* pp = part + ((size_t)P * NCH + ch) * 8;
  #pragma unroll
  for (int k = 0; k < 8; ++k)
    pp[k] = (uint16_t)((rbase + id[k]) & (NRr - 1));
}

// lex (d2, idx) insert for the merge of the chunk partials
__device__ __forceinline__ void insert_lex(float d2, int j, float (&dist)[8], int (&id)[8]) {
  bool b7 = (d2 < dist[7]) || (d2 == dist[7] && j < id[7]);
  if (b7) {
    #pragma unroll
    for (int k = 7; k >= 1; --k) {
      bool sh = (d2 < dist[k-1]) || (d2 == dist[k-1] && j < id[k-1]);
      bool pl = (d2 < dist[k])   || (d2 == dist[k]   && j < id[k]);
      float nd = sh ? dist[k-1] : (pl ? d2 : dist[k]);
      int   ni = sh ? id[k-1]   : (pl ? j  : id[k]);
      dist[k] = nd; id[k] = ni;
    }
    bool p0 = (d2 < dist[0]) || (d2 == dist[0] && j < id[0]);
    if (p0) { dist[0] = d2; id[0] = j; }
  }
}

// merge: recompute d2 exactly from ref4 (d2f) for the 256 u16 candidates
__global__ __launch_bounds__(64) void k_merge(const uint16_t* __restrict__ part,
                                              const float* __restrict__ xyz_pred,
                                              const float4* __restrict__ ref4,
                                              int* __restrict__ idx) {
  int P = blockIdx.x * 64 + threadIdx.x;    // 0..16383 (256 blocks x 64)
  int b = P >> 13;
  float px = xyz_pred[P*3+0];
  float py = xyz_pred[P*3+1];
  float pz = xyz_pred[P*3+2];
  float sp = __fadd_rn(__fadd_rn(__fmul_rn(px,px), __fmul_rn(py,py)), __fmul_rn(pz,pz));
  const float4* refbase = ref4 + (size_t)b * NRr;

  float dist[8]; int id[8];
  #pragma unroll
  for (int k = 0; k < 8; ++k) { dist[k] = 3.4e38f; id[k] = NRr - 1; }

  const ushort4* pv = (const ushort4*)(part + (size_t)P * (NCH * 8));
  for (int c = 0; c < NCH * 2; ++c) {        // 64 x ushort4 = 256 candidates
    ushort4 v = pv[c];
    int j0 = v.x & (NRr - 1), j1 = v.y & (NRr - 1);
    int j2 = v.z & (NRr - 1), j3 = v.w & (NRr - 1);
    insert_lex(d2f(px, py, pz, sp, refbase[j0]), j0, dist, id);
    insert_lex(d2f(px, py, pz, sp, refbase[j1]), j1, dist, id);
    insert_lex(d2f(px, py, pz, sp, refbase[j2]), j2, dist, id);
    insert_lex(d2f(px, py, pz, sp, refbase[j3]), j3, dist, id);
  }
  #pragma unroll
  for (int k = 0; k < 8; ++k) idx[(size_t)P*8 + k] = id[k] & (NRr - 1);
}

// ------- fold Wout@Wo@Wv -> A [512,256] bf16, bbig f32 (8 rows/block) -------
__global__ __launch_bounds__(256) void k_combine(const float* __restrict__ Wv,
    const float* __restrict__ bv, const float* __restrict__ Wo,
    const float* __restrict__ bo, const float* __restrict__ Wout,
    uint16_t* __restrict__ Aw, float* __restrict__ bbig) {
  __shared__ float M8[8][256];
  __shared__ float red[256];
  int e0 = blockIdx.x * 8;   // 0..511 in groups of 8
  int t  = threadIdx.x;      // 0..255

  float acc8[8];
  #pragma unroll
  for (int e = 0; e < 8; ++e) acc8[e] = 0.f;
  for (int d = 0; d < 256; ++d) {
    float wo = Wo[(size_t)d*256 + t];
    #pragma unroll
    for (int e = 0; e < 8; ++e)
      acc8[e] = fmaf(Wout[(size_t)(e0+e)*256 + d], wo, acc8[e]);
  }
  #pragma unroll
  for (int e = 0; e < 8; ++e) M8[e][t] = acc8[e];
  __syncthreads();

  float a8[8];
  #pragma unroll
  for (int e = 0; e < 8; ++e) a8[e] = 0.f;
  for (int c = 0; c < 256; ++c) {
    float wv = Wv[(size_t)c*256 + t];
    #pragma unroll
    for (int e = 0; e < 8; ++e)
      a8[e] = fmaf(M8[e][c], wv, a8[e]);
  }
  #pragma unroll
  for (int e = 0; e < 8; ++e) Aw[(size_t)(e0+e)*256 + t] = f2bf(a8[e]);

  for (int e = 0; e < 8; ++e) {
    red[t] = fmaf(M8[e][t], bv[t], Wout[(size_t)(e0+e)*256 + t] * bo[t]);
    __syncthreads();
    for (int s2 = 128; s2 > 0; s2 >>= 1) {
      if (t < s2) red[t] += red[t + s2];
      __syncthreads();
    }
    if (t == 0) bbig[e0+e] = red[0];
    __syncthreads();
  }
}

// ---------------- attention: one wave per pred point ------------------------
__global__ __launch_bounds__(256) void k_attn(const float* __restrict__ feat_q,
    const float* __restrict__ feat_k, const float* __restrict__ feat_v,
    const int* __restrict__ idx, uint16_t* __restrict__ g) {
  int wave = threadIdx.x >> 6;
  int lane = threadIdx.x & 63;
  int P = blockIdx.x * 4 + wave;     // 0..16383
  int b = P >> 13;
  const int* ip = idx + (size_t)P * 8;
  int nb[8];
  #pragma unroll
  for (int k = 0; k < 8; ++k) nb[k] = ip[k] & (NRr - 1);

  float4 qv = *(const float4*)(feat_q + (size_t)P*NC + lane*4);
  const float* kb = feat_k + (size_t)b * NRr * NC;
  const float* vb = feat_v + (size_t)b * NRr * NC;

  float s[8];
  #pragma unroll
  for (int k = 0; k < 8; ++k) {
    float4 kv = *(const float4*)(kb + (size_t)nb[k]*NC + lane*4);
    float p = qv.x * kv.x;
    p = fmaf(qv.y, kv.y, p);
    p = fmaf(qv.z, kv.z, p);
    p = fmaf(qv.w, kv.w, p);
    s[k] = p;
  }
  #pragma unroll
  for (int k = 0; k < 8; ++k) {
    float v = s[k];
    #pragma unroll
    for (int m = 1; m < 64; m <<= 1) v += __shfl_xor(v, m, 64);
    s[k] = v * 0.0625f;   // / sqrt(256), exact
  }
  float mx = s[0];
  #pragma unroll
  for (int k = 1; k < 8; ++k) mx = fmaxf(mx, s[k]);
  float e[8], sum = 0.f;
  #pragma unroll
  for (int k = 0; k < 8; ++k) { e[k] = expf(s[k] - mx); sum += e[k]; }
  float inv = 1.0f / sum;

  float g0 = 0.f, g1 = 0.f, g2 = 0.f, g3 = 0.f;
  #pragma unroll
  for (int k = 0; k < 8; ++k) {
    float4 vv = *(const float4*)(vb + (size_t)nb[k]*NC + lane*4);
    float w = e[k] * inv;
    g0 = fmaf(w, vv.x, g0);
    g1 = fmaf(w, vv.y, g1);
    g2 = fmaf(w, vv.z, g2);
    g3 = fmaf(w, vv.w, g3);
  }
  uint32_t p0 = ((uint32_t)f2bf(g1) << 16) | f2bf(g0);
  uint32_t p1 = ((uint32_t)f2bf(g3) << 16) | f2bf(g2);
  *(uint2*)(g + (size_t)P*NC + lane*4) = make_uint2(p0, p1);
}

// ---------------- zero-fill ref halves of output (runs LAST) ----------------
__global__ void k_zero(float4* __restrict__ o) {
  int i = blockIdx.x * 256 + threadIdx.x;  // 0 .. 2097151
  int b = i >> 20;                         // region 0 or 1
  int r = i & 1048575;                     // 1M float4 per 16MB region
  o[(size_t)b * 2097152 + r] = make_float4(0.f, 0.f, 0.f, 0.f);
}

// ---------------- final GEMM: g[16384,256]bf16 @ A^T + bbig -> f32 ----------
__global__ __launch_bounds__(256) void k_gemm(const uint16_t* __restrict__ g,
    const uint16_t* __restrict__ Aw, const float* __restrict__ bbig,
    float* __restrict__ outp) {
  // LDS stride 136 (272B): 16B-aligned rows, 4-bank shift/row => conflict-free
  __shared__ __align__(16) uint16_t sA[64 * 136];
  __shared__ __align__(16) uint16_t sB[64 * 136];
  int t = threadIdx.x;
  int lane = t & 63, wave = t >> 6;
  int wm = (wave >> 1) * 32, wn = (wave & 1) * 32;
  int q = lane >> 4, rr = lane & 15;
  int bm = blockIdx.x;   // 0..255 (M tiles of 64)
  int bn = blockIdx.y;   // 0..7   (N tiles of 64)
  f32x4 zero = {0.f, 0.f, 0.f, 0.f};
  f32x4 acc[2][2] = {{zero, zero}, {zero, zero}};

  for (int ph = 0; ph < 2; ++ph) {      // K = 256 in two 128 phases
    #pragma unroll
    for (int i = 0; i < 4; ++i) {
      int cc  = t + i * 256;            // 0..1023 chunks of 8 bf16
      int row = cc >> 4;                // 16 chunks per row
      int col = (cc & 15) << 3;
      uint4 da = *(const uint4*)(g  + ((size_t)(bm*64 + row))*NC + ph*128 + col);
      *(uint4*)(&sA[row*136 + col]) = da;
      uint4 db = *(const uint4*)(Aw + ((size_t)(bn*64 + row))*NC + ph*128 + col);
      *(uint4*)(&sB[row*136 + col]) = db;
    }
    __syncthreads();
    #pragma unroll
    for (int kk = 0; kk < 4; ++kk) {
      int ko = kk*32 + q*8;
      bf16x8 a0 = *(const bf16x8*)(&sA[(wm      + rr)*136 + ko]);
      bf16x8 a1 = *(const bf16x8*)(&sA[(wm + 16 + rr)*136 + ko]);
      bf16x8 b0 = *(const bf16x8*)(&sB[(wn      + rr)*136 + ko]);
      bf16x8 b1 = *(const bf16x8*)(&sB[(wn + 16 + rr)*136 + ko]);
      acc[0][0] = __builtin_amdgcn_mfma_f32_16x16x32_bf16(a0, b0, acc[0][0], 0, 0, 0);
      acc[0][1] = __builtin_amdgcn_mfma_f32_16x16x32_bf16(a0, b1, acc[0][1], 0, 0, 0);
      acc[1][0] = __builtin_amdgcn_mfma_f32_16x16x32_bf16(a1, b0, acc[1][0], 0, 0, 0);
      acc[1][1] = __builtin_amdgcn_mfma_f32_16x16x32_bf16(a1, b1, acc[1][1], 0, 0, 0);
    }
    __syncthreads();
  }
  #pragma unroll
  for (int j = 0; j < 2; ++j) {
    int col = bn*64 + wn + j*16 + rr;
    float bias = bbig[col];
    #pragma unroll
    for (int i = 0; i < 2; ++i) {
      #pragma unroll
      for (int r = 0; r < 4; ++r) {
        int row = bm*64 + wm + i*16 + q*4 + r;   // C/D: col=lane&15, row=(lane>>4)*4+reg
        float v = acc[i][j][r] + bias;
        int bb = row >> 13, p = row & 8191;
        outp[((size_t)(bb*16384 + 8192 + p))*512 + col] = v;
      }
    }
  }
}

extern "C" void kernel_launch(void* const* d_in, const int* in_sizes, int n_in,
                              void* d_out, int out_size, void* d_ws, size_t ws_size,
                              hipStream_t stream) {
  const float* xyz_ref  = (const float*)d_in[0];
  const float* xyz_pred = (const float*)d_in[1];
  const float* feat_k   = (const float*)d_in[2];
  const float* feat_q   = (const float*)d_in[3];
  const float* feat_v   = (const float*)d_in[4];
  const float* Wv       = (const float*)d_in[5];
  const float* bv       = (const float*)d_in[6];
  const float* Wo       = (const float*)d_in[7];
  const float* bo       = (const float*)d_in[8];
  const float* Wout     = (const float*)d_in[9];
  float* outp = (float*)d_out;

  // ALL scratch inside d_out's dead ref-half regions (f32 output, 64MB):
  char* ob = (char*)d_out;
  uint16_t* g    = (uint16_t*)ob;                    // [0, 8M)    bf16 16384x256
  float4*   ref4 = (float4*)(ob + 8388608);          // [8M, 8.25M)
  int*      idx  = (int*)(ob + 8650752);             // [8.25M, 8.75M)
  uint16_t* Aw   = (uint16_t*)(ob + 9175040);        // [8.75M, 9M)
  float*    bbig = (float*)(ob + 9437184);           // [9M, +2K)
  uint16_t* part = (uint16_t*)(ob + 33554432);       // [32M, 40M)  8 MB u16

  k_prep   <<<256,  64,  0, stream>>>(xyz_ref, ref4);
  k_knn    <<<2048, 256, 0, stream>>>(xyz_pred, ref4, part);
  k_merge  <<<256,  64,  0, stream>>>(part, xyz_pred, ref4, idx);
  k_combine<<<64,   256, 0, stream>>>(Wv, bv, Wo, bo, Wout, Aw, bbig);
  k_attn   <<<4096, 256, 0, stream>>>(feat_q, feat_k, feat_v, idx, g);
  k_gemm   <<<dim3(256, 8), 256, 0, stream>>>(g, Aw, bbig, outp);
  k_zero   <<<8192, 256, 0, stream>>>((float4*)outp);
}

// Round 7
// 441.585 us; speedup vs baseline: 1.0216x; 1.0216x over previous
//
#include <hip/hip_runtime.h>
#include <stdint.h>

// CrossAttn: B=2, Nr=Np=8192, C=256, K=8. ALL I/O float32.
// R17: k_knn = R15's LDS hot loop (dual 4-chain + running-tau mask, proven
// passing at 155.8us) with ONE change: __launch_bounds__(256,8)->(256,6).
// Evidence: (256,8) pinned VGPR=32; FETCH/WRITE_SIZE show ~14MB/dispatch of
// scratch spills since R15 (R14 988/8192KB clean -> R16 5107/18432KB), and
// the ~50 instr/cand gap between static and measured appeared exactly when
// the 32-reg cap did (R9 @ VGPR20 matched static 1:1). (256,6) still forces
// <=64 VGPR (65+ would drop to 4 waves/SIMD < 6) but doubles the allocator's
// budget: chains(8)+dist/id(16)+coords(4)+addr fit without spill/juggle.
// R16's readlane variant reverted (measured wash vs LDS reads).
// Everything else unchanged from R16 (passing, 451us).
// Scratch: NO d_ws. All inside d_out dead ref-half regions:
//   g 8MB [0,8M); ref4 [8M,..); idx [8.25M,..); Aw [8.75M,..); bbig [9M,..);
//   part u16 8MB [32M,40M).
// k_gemm writes pred halves [16M,32M)+[48M,64M); k_zero zeroes ref halves LAST.

#define NRr 8192
#define NPp 8192
#define NC  256
#define NK  8
#define NCH   32     // ref chunks
#define CHUNK 256    // refs per chunk

typedef short bf16x8 __attribute__((ext_vector_type(8)));
typedef float f32x4  __attribute__((ext_vector_type(4)));

__device__ __forceinline__ uint16_t f2bf(float f) {
  uint32_t u = __float_as_uint(f);
  return (uint16_t)((u + 0x7fffu + ((u >> 16) & 1u)) >> 16);
}

// Exact np-f32 d2: rounded products, sequential adds, (sp+sr) - (dot+dot).
// Used by k_knn (all passes) and k_merge so recomputation is bitwise identical.
__device__ __forceinline__ float d2f(float px, float py, float pz, float sp, float4 r) {
  float m0 = __fmul_rn(px, r.x), m1 = __fmul_rn(py, r.y), m2 = __fmul_rn(pz, r.z);
  float dot = __fadd_rn(__fadd_rn(m0, m1), m2);
  return __fsub_rn(__fadd_rn(sp, r.w), __fadd_rn(dot, dot));
}

// ---------------- prep: ref coords + |r|^2 (literal np rounding) ------------
__global__ __launch_bounds__(64) void k_prep(const float* __restrict__ xyz_ref,
                                             float4* __restrict__ ref4) {
  int i = blockIdx.x * 64 + threadIdx.x;       // 0 .. 2*NR-1 (256 blocks x 64)
  if (i >= 2 * NRr) return;
  float x = xyz_ref[i*3+0];
  float y = xyz_ref[i*3+1];
  float z = xyz_ref[i*3+2];
  float n = __fadd_rn(__fadd_rn(__fmul_rn(x,x), __fmul_rn(y,y)), __fmul_rn(z,z));
  ref4[i] = make_float4(x, y, z, n);
}

// sorted-8 insert, strict < on d2 (scan order ascending idx => lex-stable)
__device__ __forceinline__ void insert8(float d2, int j, float (&dist)[8], int (&id)[8]) {
  if (d2 < dist[7]) {
    #pragma unroll
    for (int k = 7; k >= 1; --k) {
      bool sh = d2 < dist[k-1];
      bool pl = d2 < dist[k];
      float nd = sh ? dist[k-1] : (pl ? d2 : dist[k]);
      int   ni = sh ? id[k-1]   : (pl ? j  : id[k]);
      dist[k] = nd; id[k] = ni;
    }
    if (d2 < dist[0]) { dist[0] = d2; id[0] = j; }
  }
}

// ---- brute-force KNN: 4 independent single-wave bodies per 256-thr block ---
// wave-task = blockIdx*4 + wave; ch = task & 31; point-group = task >> 5.
// Each wave stages its OWN LDS segments and never reads another wave's:
// no barrier, no cross-wave coupling.
__global__ __launch_bounds__(256, 6) void k_knn(const float* __restrict__ xyz_pred,
                                                const float4* __restrict__ ref4,
                                                uint16_t* __restrict__ part) {
  __shared__ __align__(16) float4 sref[4][CHUNK];   // 16 KB
  __shared__ uint32_t smask[4][4 * 64];             //  4 KB (per-half masks)
  int wave = threadIdx.x >> 6;
  int lane = threadIdx.x & 63;
  int task = blockIdx.x * 4 + wave;            // 0..8191
  int ch   = task & (NCH - 1);                 // 0..31
  int P    = (task >> 5) * 64 + lane;          // global point 0..16383
  int b    = P >> 13;

  float px = xyz_pred[P*3+0];
  float py = xyz_pred[P*3+1];
  float pz = xyz_pred[P*3+2];
  float sp = __fadd_rn(__fadd_rn(__fmul_rn(px,px), __fmul_rn(py,py)), __fmul_rn(pz,pz));

  const float4* refbase = ref4 + (size_t)b * NRr;
  int rbase = ch * CHUNK;
  for (int j = lane; j < CHUNK; j += 64) sref[wave][j] = refbase[rbase + j];
  // no __syncthreads: in-wave ds_write -> ds_read ordering via lgkmcnt

  // dual 4-chains: a = top-4 of evens, g = top-4 of odds (ascending order)
  float a0 = 3.4e38f, a1 = 3.4e38f, a2 = 3.4e38f, a3 = 3.4e38f;
  float g0 = 3.4e38f, g1 = 3.4e38f, g2 = 3.4e38f, g3 = 3.4e38f;
  float dist[8]; int id[8];
  #pragma unroll
  for (int k = 0; k < 8; ++k) { dist[k] = 3.4e38f; id[k] = 0; }

  for (int h = 0; h < 2; ++h) {                // two half-chunks of 128
    // ---- fused mask pass over this half (4 segments x 32 candidates) ------
    for (int s = 0; s < 4; ++s) {
      uint32_t mm = 0;
      int base = h * 128 + s * 32;
      #pragma unroll 2
      for (int jj = 0; jj < 32; jj += 2) {
        float d0 = d2f(px, py, pz, sp, sref[wave][base + jj]);
        float d1 = d2f(px, py, pz, sp, sref[wave][base + jj + 1]);
        // chain A <- even candidate (reads pre-update lower slots: top-down)
        a3 = fminf(fmaxf(d0, a2), a3);
        a2 = fminf(fmaxf(d0, a1), a2);
        a1 = fminf(fmaxf(d0, a0), a1);
        a0 = fminf(d0, a0);
        // chain G <- odd candidate
        g3 = fminf(fmaxf(d1, g2), g3);
        g2 = fminf(fmaxf(d1, g1), g2);
        g1 = fminf(fmaxf(d1, g0), g1);
        g0 = fminf(d1, g0);
        float tau = fmaxf(a3, g3);             // >= running 8th >= final T8
        mm |= (uint32_t)(d0 <= tau) << jj;
        mm |= (uint32_t)(d1 <= tau) << (jj + 1);
      }
      smask[wave][s*64 + lane] = mm;
    }
    // ---- finalize this half's survivors (ascending j, strict <) -----------
    for (int s = 0; s < 4; ++s) {
      uint32_t mm = smask[wave][s*64 + lane];
      int base = h * 128 + s * 32;
      while (mm) {
        int bit = __builtin_ctz(mm); mm &= mm - 1;
        int j = base + bit;
        float dd = d2f(px, py, pz, sp, sref[wave][j]);
        insert8(dd, j, dist, id);
      }
    }
  }

  uint16_t* pp = part + ((size_t)P * NCH + ch) * 8;
  #pragma unroll
  for (int k = 0; k < 8; ++k)
    pp[k] = (uint16_t)((rbase + id[k]) & (NRr - 1));
}

// lex (d2, idx) insert for the merge of the chunk partials
__device__ __forceinline__ void insert_lex(float d2, int j, float (&dist)[8], int (&id)[8]) {
  bool b7 = (d2 < dist[7]) || (d2 == dist[7] && j < id[7]);
  if (b7) {
    #pragma unroll
    for (int k = 7; k >= 1; --k) {
      bool sh = (d2 < dist[k-1]) || (d2 == dist[k-1] && j < id[k-1]);
      bool pl = (d2 < dist[k])   || (d2 == dist[k]   && j < id[k]);
      float nd = sh ? dist[k-1] : (pl ? d2 : dist[k]);
      int   ni = sh ? id[k-1]   : (pl ? j  : id[k]);
      dist[k] = nd; id[k] = ni;
    }
    bool p0 = (d2 < dist[0]) || (d2 == dist[0] && j < id[0]);
    if (p0) { dist[0] = d2; id[0] = j; }
  }
}

// merge: recompute d2 exactly from ref4 (d2f) for the 256 u16 candidates
__global__ __launch_bounds__(64) void k_merge(const uint16_t* __restrict__ part,
                                              const float* __restrict__ xyz_pred,
                                              const float4* __restrict__ ref4,
                                              int* __restrict__ idx) {
  int P = blockIdx.x * 64 + threadIdx.x;    // 0..16383 (256 blocks x 64)
  int b = P >> 13;
  float px = xyz_pred[P*3+0];
  float py = xyz_pred[P*3+1];
  float pz = xyz_pred[P*3+2];
  float sp = __fadd_rn(__fadd_rn(__fmul_rn(px,px), __fmul_rn(py,py)), __fmul_rn(pz,pz));
  const float4* refbase = ref4 + (size_t)b * NRr;

  float dist[8]; int id[8];
  #pragma unroll
  for (int k = 0; k < 8; ++k) { dist[k] = 3.4e38f; id[k] = NRr - 1; }

  const ushort4* pv = (const ushort4*)(part + (size_t)P * (NCH * 8));
  for (int c = 0; c < NCH * 2; ++c) {        // 64 x ushort4 = 256 candidates
    ushort4 v = pv[c];
    int j0 = v.x & (NRr - 1), j1 = v.y & (NRr - 1);
    int j2 = v.z & (NRr - 1), j3 = v.w & (NRr - 1);
    insert_lex(d2f(px, py, pz, sp, refbase[j0]), j0, dist, id);
    insert_lex(d2f(px, py, pz, sp, refbase[j1]), j1, dist, id);
    insert_lex(d2f(px, py, pz, sp, refbase[j2]), j2, dist, id);
    insert_lex(d2f(px, py, pz, sp, refbase[j3]), j3, dist, id);
  }
  #pragma unroll
  for (int k = 0; k < 8; ++k) idx[(size_t)P*8 + k] = id[k] & (NRr - 1);
}

// ------- fold Wout@Wo@Wv -> A [512,256] bf16, bbig f32 (8 rows/block) -------
__global__ __launch_bounds__(256) void k_combine(const float* __restrict__ Wv,
    const float* __restrict__ bv, const float* __restrict__ Wo,
    const float* __restrict__ bo, const float* __restrict__ Wout,
    uint16_t* __restrict__ Aw, float* __restrict__ bbig) {
  __shared__ float M8[8][256];
  __shared__ float red[256];
  int e0 = blockIdx.x * 8;   // 0..511 in groups of 8
  int t  = threadIdx.x;      // 0..255

  float acc8[8];
  #pragma unroll
  for (int e = 0; e < 8; ++e) acc8[e] = 0.f;
  for (int d = 0; d < 256; ++d) {
    float wo = Wo[(size_t)d*256 + t];
    #pragma unroll
    for (int e = 0; e < 8; ++e)
      acc8[e] = fmaf(Wout[(size_t)(e0+e)*256 + d], wo, acc8[e]);
  }
  #pragma unroll
  for (int e = 0; e < 8; ++e) M8[e][t] = acc8[e];
  __syncthreads();

  float a8[8];
  #pragma unroll
  for (int e = 0; e < 8; ++e) a8[e] = 0.f;
  for (int c = 0; c < 256; ++c) {
    float wv = Wv[(size_t)c*256 + t];
    #pragma unroll
    for (int e = 0; e < 8; ++e)
      a8[e] = fmaf(M8[e][c], wv, a8[e]);
  }
  #pragma unroll
  for (int e = 0; e < 8; ++e) Aw[(size_t)(e0+e)*256 + t] = f2bf(a8[e]);

  for (int e = 0; e < 8; ++e) {
    red[t] = fmaf(M8[e][t], bv[t], Wout[(size_t)(e0+e)*256 + t] * bo[t]);
    __syncthreads();
    for (int s2 = 128; s2 > 0; s2 >>= 1) {
      if (t < s2) red[t] += red[t + s2];
      __syncthreads();
    }
    if (t == 0) bbig[e0+e] = red[0];
    __syncthreads();
  }
}

// ---------------- attention: one wave per pred point ------------------------
__global__ __launch_bounds__(256) void k_attn(const float* __restrict__ feat_q,
    const float* __restrict__ feat_k, const float* __restrict__ feat_v,
    const int* __restrict__ idx, uint16_t* __restrict__ g) {
  int wave = threadIdx.x >> 6;
  int lane = threadIdx.x & 63;
  int P = blockIdx.x * 4 + wave;     // 0..16383
  int b = P >> 13;
  const int* ip = idx + (size_t)P * 8;
  int nb[8];
  #pragma unroll
  for (int k = 0; k < 8; ++k) nb[k] = ip[k] & (NRr - 1);

  float4 qv = *(const float4*)(feat_q + (size_t)P*NC + lane*4);
  const float* kb = feat_k + (size_t)b * NRr * NC;
  const float* vb = feat_v + (size_t)b * NRr * NC;

  float s[8];
  #pragma unroll
  for (int k = 0; k < 8; ++k) {
    float4 kv = *(const float4*)(kb + (size_t)nb[k]*NC + lane*4);
    float p = qv.x * kv.x;
    p = fmaf(qv.y, kv.y, p);
    p = fmaf(qv.z, kv.z, p);
    p = fmaf(qv.w, kv.w, p);
    s[k] = p;
  }
  #pragma unroll
  for (int k = 0; k < 8; ++k) {
    float v = s[k];
    #pragma unroll
    for (int m = 1; m < 64; m <<= 1) v += __shfl_xor(v, m, 64);
    s[k] = v * 0.0625f;   // / sqrt(256), exact
  }
  float mx = s[0];
  #pragma unroll
  for (int k = 1; k < 8; ++k) mx = fmaxf(mx, s[k]);
  float e[8], sum = 0.f;
  #pragma unroll
  for (int k = 0; k < 8; ++k) { e[k] = expf(s[k] - mx); sum += e[k]; }
  float inv = 1.0f / sum;

  float g0 = 0.f, g1 = 0.f, g2 = 0.f, g3 = 0.f;
  #pragma unroll
  for (int k = 0; k < 8; ++k) {
    float4 vv = *(const float4*)(vb + (size_t)nb[k]*NC + lane*4);
    float w = e[k] * inv;
    g0 = fmaf(w, vv.x, g0);
    g1 = fmaf(w, vv.y, g1);
    g2 = fmaf(w, vv.z, g2);
    g3 = fmaf(w, vv.w, g3);
  }
  uint32_t p0 = ((uint32_t)f2bf(g1) << 16) | f2bf(g0);
  uint32_t p1 = ((uint32_t)f2bf(g3) << 16) | f2bf(g2);
  *(uint2*)(g + (size_t)P*NC + lane*4) = make_uint2(p0, p1);
}

// ---------------- zero-fill ref halves of output (runs LAST) ----------------
__global__ void k_zero(float4* __restrict__ o) {
  int i = blockIdx.x * 256 + threadIdx.x;  // 0 .. 2097151
  int b = i >> 20;                         // region 0 or 1
  int r = i & 1048575;                     // 1M float4 per 16MB region
  o[(size_t)b * 2097152 + r] = make_float4(0.f, 0.f, 0.f, 0.f);
}

// ---------------- final GEMM: g[16384,256]bf16 @ A^T + bbig -> f32 ----------
__global__ __launch_bounds__(256) void k_gemm(const uint16_t* __restrict__ g,
    const uint16_t* __restrict__ Aw, const float* __restrict__ bbig,
    float* __restrict__ outp) {
  // LDS stride 136 (272B): 16B-aligned rows, 4-bank shift/row => conflict-free
  __shared__ __align__(16) uint16_t sA[64 * 136];
  __shared__ __align__(16) uint16_t sB[64 * 136];
  int t = threadIdx.x;
  int lane = t & 63, wave = t >> 6;
  int wm = (wave >> 1) * 32, wn = (wave & 1) * 32;
  int q = lane >> 4, rr = lane & 15;
  int bm = blockIdx.x;   // 0..255 (M tiles of 64)
  int bn = blockIdx.y;   // 0..7   (N tiles of 64)
  f32x4 zero = {0.f, 0.f, 0.f, 0.f};
  f32x4 acc[2][2] = {{zero, zero}, {zero, zero}};

  for (int ph = 0; ph < 2; ++ph) {      // K = 256 in two 128 phases
    #pragma unroll
    for (int i = 0; i < 4; ++i) {
      int cc  = t + i * 256;            // 0..1023 chunks of 8 bf16
      int row = cc >> 4;                // 16 chunks per row
      int col = (cc & 15) << 3;
      uint4 da = *(const uint4*)(g  + ((size_t)(bm*64 + row))*NC + ph*128 + col);
      *(uint4*)(&sA[row*136 + col]) = da;
      uint4 db = *(const uint4*)(Aw + ((size_t)(bn*64 + row))*NC + ph*128 + col);
      *(uint4*)(&sB[row*136 + col]) = db;
    }
    __syncthreads();
    #pragma unroll
    for (int kk = 0; kk < 4; ++kk) {
      int ko = kk*32 + q*8;
      bf16x8 a0 = *(const bf16x8*)(&sA[(wm      + rr)*136 + ko]);
      bf16x8 a1 = *(const bf16x8*)(&sA[(wm + 16 + rr)*136 + ko]);
      bf16x8 b0 = *(const bf16x8*)(&sB[(wn      + rr)*136 + ko]);
      bf16x8 b1 = *(const bf16x8*)(&sB[(wn + 16 + rr)*136 + ko]);
      acc[0][0] = __builtin_amdgcn_mfma_f32_16x16x32_bf16(a0, b0, acc[0][0], 0, 0, 0);
      acc[0][1] = __builtin_amdgcn_mfma_f32_16x16x32_bf16(a0, b1, acc[0][1], 0, 0, 0);
      acc[1][0] = __builtin_amdgcn_mfma_f32_16x16x32_bf16(a1, b0, acc[1][0], 0, 0, 0);
      acc[1][1] = __builtin_amdgcn_mfma_f32_16x16x32_bf16(a1, b1, acc[1][1], 0, 0, 0);
    }
    __syncthreads();
  }
  #pragma unroll
  for (int j = 0; j < 2; ++j) {
    int col = bn*64 + wn + j*16 + rr;
    float bias = bbig[col];
    #pragma unroll
    for (int i = 0; i < 2; ++i) {
      #pragma unroll
      for (int r = 0; r < 4; ++r) {
        int row = bm*64 + wm + i*16 + q*4 + r;   // C/D: col=lane&15, row=(lane>>4)*4+reg
        float v = acc[i][j][r] + bias;
        int bb = row >> 13, p = row & 8191;
        outp[((size_t)(bb*16384 + 8192 + p))*512 + col] = v;
      }
    }
  }
}

extern "C" void kernel_launch(void* const* d_in, const int* in_sizes, int n_in,
                              void* d_out, int out_size, void* d_ws, size_t ws_size,
                              hipStream_t stream) {
  const float* xyz_ref  = (const float*)d_in[0];
  const float* xyz_pred = (const float*)d_in[1];
  const float* feat_k   = (const float*)d_in[2];
  const float* feat_q   = (const float*)d_in[3];
  const float* feat_v   = (const float*)d_in[4];
  const float* Wv       = (const float*)d_in[5];
  const float* bv       = (const float*)d_in[6];
  const float* Wo       = (const float*)d_in[7];
  const float* bo       = (const float*)d_in[8];
  const float* Wout     = (const float*)d_in[9];
  float* outp = (float*)d_out;

  // ALL scratch inside d_out's dead ref-half regions (f32 output, 64MB):
  char* ob = (char*)d_out;
  uint16_t* g    = (uint16_t*)ob;                    // [0, 8M)    bf16 16384x256
  float4*   ref4 = (float4*)(ob + 8388608);          // [8M, 8.25M)
  int*      idx  = (int*)(ob + 8650752);             // [8.25M, 8.75M)
  uint16_t* Aw   = (uint16_t*)(ob + 9175040);        // [8.75M, 9M)
  float*    bbig = (float*)(ob + 9437184);           // [9M, +2K)
  uint16_t* part = (uint16_t*)(ob + 33554432);       // [32M, 40M)  8 MB u16

  k_prep   <<<256,  64,  0, stream>>>(xyz_ref, ref4);
  k_knn    <<<2048, 256, 0, stream>>>(xyz_pred, ref4, part);
  k_merge  <<<256,  64,  0, stream>>>(part, xyz_pred, ref4, idx);
  k_combine<<<64,   256, 0, stream>>>(Wv, bv, Wo, bo, Wout, Aw, bbig);
  k_attn   <<<4096, 256, 0, stream>>>(feat_q, feat_k, feat_v, idx, g);
  k_gemm   <<<dim3(256, 8), 256, 0, stream>>>(g, Aw, bbig, outp);
  k_zero   <<<8192, 256, 0, stream>>>((float4*)outp);
}

// Round 8
// 436.993 us; speedup vs baseline: 1.0323x; 1.0105x over previous
//
#include <hip/hip_runtime.h>
#include <stdint.h>

// CrossAttn: B=2, Nr=Np=8192, C=256, K=8. ALL I/O float32.
// R18: k_knn = R16's readlane hot loop (zero LDS in the inner loop), made
// spill-free. R17 proved spills weren't the cost (FETCH/WRITE normalized,
// time ~unchanged) -> model says the wave-broadcast ds_read_b128 per cand
// (~10cyc of the CU-shared LDS pipe vs ~38cyc VALU) puts 4 hot SIMDs at
// ~105% of the LDS pipe: k_knn is LDS-issue co-limited. Readlane moves the
// broadcast to the VALU (4 v_readlane/cand into SGPRs, 1 SGPR/instr is legal)
// and frees the LDS pipe. R16 tested this but at (256,8)/VGPR32 it spilled
// (FETCH 5107/WRITE 18432) and masked the gain; now (256,6) (<=64 VGPR,
// live set ~56). Chains use v_med3_f32 (== min(max) for sorted chain,
// median is order-invariant => bit-exact; exonerates med3 from R11 whose
// real suspect was the LDS byte buffer). Finalize (exact d2f, strict-<,
// ascending j over superset mask) unchanged => part[] bit-identical.
// Everything else unchanged from R17 (passing, 441.6us).
// Scratch: NO d_ws. All inside d_out dead ref-half regions:
//   g 8MB [0,8M); ref4 [8M,..); idx [8.25M,..); Aw [8.75M,..); bbig [9M,..);
//   part u16 8MB [32M,40M).
// k_gemm writes pred halves [16M,32M)+[48M,64M); k_zero zeroes ref halves LAST.

#define NRr 8192
#define NPp 8192
#define NC  256
#define NK  8
#define NCH   32     // ref chunks
#define CHUNK 256    // refs per chunk

typedef short bf16x8 __attribute__((ext_vector_type(8)));
typedef float f32x4  __attribute__((ext_vector_type(4)));

__device__ __forceinline__ uint16_t f2bf(float f) {
  uint32_t u = __float_as_uint(f);
  return (uint16_t)((u + 0x7fffu + ((u >> 16) & 1u)) >> 16);
}

// Exact np-f32 d2: rounded products, sequential adds, (sp+sr) - (dot+dot).
// Used by k_knn (all passes) and k_merge so recomputation is bitwise identical.
__device__ __forceinline__ float d2f(float px, float py, float pz, float sp, float4 r) {
  float m0 = __fmul_rn(px, r.x), m1 = __fmul_rn(py, r.y), m2 = __fmul_rn(pz, r.z);
  float dot = __fadd_rn(__fadd_rn(m0, m1), m2);
  return __fsub_rn(__fadd_rn(sp, r.w), __fadd_rn(dot, dot));
}

// ---------------- prep: ref coords + |r|^2 (literal np rounding) ------------
__global__ __launch_bounds__(64) void k_prep(const float* __restrict__ xyz_ref,
                                             float4* __restrict__ ref4) {
  int i = blockIdx.x * 64 + threadIdx.x;       // 0 .. 2*NR-1 (256 blocks x 64)
  if (i >= 2 * NRr) return;
  float x = xyz_ref[i*3+0];
  float y = xyz_ref[i*3+1];
  float z = xyz_ref[i*3+2];
  float n = __fadd_rn(__fadd_rn(__fmul_rn(x,x), __fmul_rn(y,y)), __fmul_rn(z,z));
  ref4[i] = make_float4(x, y, z, n);
}

// sorted-8 insert, strict < on d2 (scan order ascending idx => lex-stable)
__device__ __forceinline__ void insert8(float d2, int j, float (&dist)[8], int (&id)[8]) {
  if (d2 < dist[7]) {
    #pragma unroll
    for (int k = 7; k >= 1; --k) {
      bool sh = d2 < dist[k-1];
      bool pl = d2 < dist[k];
      float nd = sh ? dist[k-1] : (pl ? d2 : dist[k]);
      int   ni = sh ? id[k-1]   : (pl ? j  : id[k]);
      dist[k] = nd; id[k] = ni;
    }
    if (d2 < dist[0]) { dist[0] = d2; id[0] = j; }
  }
}

// broadcast lane L's candidate float4 (wave-uniform L) into all lanes
__device__ __forceinline__ float4 bcast4(uint32_t cx, uint32_t cy,
                                         uint32_t cz, uint32_t cw, int L) {
  return make_float4(__uint_as_float(__builtin_amdgcn_readlane(cx, L)),
                     __uint_as_float(__builtin_amdgcn_readlane(cy, L)),
                     __uint_as_float(__builtin_amdgcn_readlane(cz, L)),
                     __uint_as_float(__builtin_amdgcn_readlane(cw, L)));
}

// one 64-candidate block: readlane broadcast, dual 4-chains (med3), per-half
// mask + immediate finalize (ascending j: bq asc, half asc, ctz asc)
__device__ __forceinline__ void kblock(float4 rc, int bq,
    float px, float py, float pz, float sp,
    float &a0, float &a1, float &a2, float &a3,
    float &g0, float &g1, float &g2, float &g3,
    float (&dist)[8], int (&id)[8], const float4* srefw) {
  uint32_t cx = __float_as_uint(rc.x), cy = __float_as_uint(rc.y);
  uint32_t cz = __float_as_uint(rc.z), cw = __float_as_uint(rc.w);
  #pragma unroll
  for (int half = 0; half < 2; ++half) {
    uint32_t mm = 0;
    #pragma unroll 4
    for (int t = 0; t < 32; t += 2) {
      int L0 = half*32 + t;
      float4 r0 = bcast4(cx, cy, cz, cw, L0);
      float4 r1 = bcast4(cx, cy, cz, cw, L0 + 1);
      float d0 = d2f(px, py, pz, sp, r0);
      float d1 = d2f(px, py, pz, sp, r1);
      // chain A <- even candidate; med3(x,lo,hi) == sorted-insert shift
      a3 = __builtin_amdgcn_fmed3f(d0, a2, a3);
      a2 = __builtin_amdgcn_fmed3f(d0, a1, a2);
      a1 = __builtin_amdgcn_fmed3f(d0, a0, a1);
      a0 = fminf(d0, a0);
      // chain G <- odd candidate
      g3 = __builtin_amdgcn_fmed3f(d1, g2, g3);
      g2 = __builtin_amdgcn_fmed3f(d1, g1, g2);
      g1 = __builtin_amdgcn_fmed3f(d1, g0, g1);
      g0 = fminf(d1, g0);
      float tau = fmaxf(a3, g3);               // >= running 8th >= final T8
      mm |= (uint32_t)(d0 <= tau) << t;
      mm |= (uint32_t)(d1 <= tau) << (t + 1);
    }
    // finalize this half's survivors (ascending j, strict <)
    int jb = bq*64 + half*32;
    while (mm) {
      int bit = __builtin_ctz(mm); mm &= mm - 1;
      int j = jb + bit;
      float dd = d2f(px, py, pz, sp, srefw[j]);
      insert8(dd, j, dist, id);
    }
  }
}

// ---- brute-force KNN: 4 independent single-wave bodies per 256-thr block ---
// wave-task = blockIdx*4 + wave; ch = task & 31; point-group = task >> 5.
// Each wave stages its OWN LDS segment and never reads another wave's:
// no barrier, no cross-wave coupling.
__global__ __launch_bounds__(256, 6) void k_knn(const float* __restrict__ xyz_pred,
                                                const float4* __restrict__ ref4,
                                                uint16_t* __restrict__ part) {
  __shared__ __align__(16) float4 sref[4][CHUNK];   // 16 KB (finalize only)
  int wave = threadIdx.x >> 6;
  int lane = threadIdx.x & 63;
  int task = blockIdx.x * 4 + wave;            // 0..8191
  int ch   = task & (NCH - 1);                 // 0..31
  int P    = (task >> 5) * 64 + lane;          // global point 0..16383
  int b    = P >> 13;

  float px = xyz_pred[P*3+0];
  float py = xyz_pred[P*3+1];
  float pz = xyz_pred[P*3+2];
  float sp = __fadd_rn(__fadd_rn(__fmul_rn(px,px), __fmul_rn(py,py)), __fmul_rn(pz,pz));

  const float4* refbase = ref4 + (size_t)b * NRr;
  int rbase = ch * CHUNK;

  // each lane owns candidate (bq*64 + lane); mirror to LDS for finalize reads
  float4 rc0 = refbase[rbase +   0 + lane];
  float4 rc1 = refbase[rbase +  64 + lane];
  float4 rc2 = refbase[rbase + 128 + lane];
  float4 rc3 = refbase[rbase + 192 + lane];
  sref[wave][  0 + lane] = rc0;
  sref[wave][ 64 + lane] = rc1;
  sref[wave][128 + lane] = rc2;
  sref[wave][192 + lane] = rc3;
  // no __syncthreads: in-wave ds_write -> ds_read ordering via lgkmcnt

  float a0 = 3.4e38f, a1 = 3.4e38f, a2 = 3.4e38f, a3 = 3.4e38f;
  float g0 = 3.4e38f, g1 = 3.4e38f, g2 = 3.4e38f, g3 = 3.4e38f;
  float dist[8]; int id[8];
  #pragma unroll
  for (int k = 0; k < 8; ++k) { dist[k] = 3.4e38f; id[k] = 0; }

  const float4* srefw = &sref[wave][0];
  kblock(rc0, 0, px, py, pz, sp, a0, a1, a2, a3, g0, g1, g2, g3, dist, id, srefw);
  kblock(rc1, 1, px, py, pz, sp, a0, a1, a2, a3, g0, g1, g2, g3, dist, id, srefw);
  kblock(rc2, 2, px, py, pz, sp, a0, a1, a2, a3, g0, g1, g2, g3, dist, id, srefw);
  kblock(rc3, 3, px, py, pz, sp, a0, a1, a2, a3, g0, g1, g2, g3, dist, id, srefw);

  uint16_t* pp = part + ((size_t)P * NCH + ch) * 8;
  #pragma unroll
  for (int k = 0; k < 8; ++k)
    pp[k] = (uint16_t)((rbase + id[k]) & (NRr - 1));
}

// lex (d2, idx) insert for the merge of the chunk partials
__device__ __forceinline__ void insert_lex(float d2, int j, float (&dist)[8], int (&id)[8]) {
  bool b7 = (d2 < dist[7]) || (d2 == dist[7] && j < id[7]);
  if (b7) {
    #pragma unroll
    for (int k = 7; k >= 1; --k) {
      bool sh = (d2 < dist[k-1]) || (d2 == dist[k-1] && j < id[k-1]);
      bool pl = (d2 < dist[k])   || (d2 == dist[k]   && j < id[k]);
      float nd = sh ? dist[k-1] : (pl ? d2 : dist[k]);
      int   ni = sh ? id[k-1]   : (pl ? j  : id[k]);
      dist[k] = nd; id[k] = ni;
    }
    bool p0 = (d2 < dist[0]) || (d2 == dist[0] && j < id[0]);
    if (p0) { dist[0] = d2; id[0] = j; }
  }
}

// merge: recompute d2 exactly from ref4 (d2f) for the 256 u16 candidates
__global__ __launch_bounds__(64) void k_merge(const uint16_t* __restrict__ part,
                                              const float* __restrict__ xyz_pred,
                                              const float4* __restrict__ ref4,
                                              int* __restrict__ idx) {
  int P = blockIdx.x * 64 + threadIdx.x;    // 0..16383 (256 blocks x 64)
  int b = P >> 13;
  float px = xyz_pred[P*3+0];
  float py = xyz_pred[P*3+1];
  float pz = xyz_pred[P*3+2];
  float sp = __fadd_rn(__fadd_rn(__fmul_rn(px,px), __fmul_rn(py,py)), __fmul_rn(pz,pz));
  const float4* refbase = ref4 + (size_t)b * NRr;

  float dist[8]; int id[8];
  #pragma unroll
  for (int k = 0; k < 8; ++k) { dist[k] = 3.4e38f; id[k] = NRr - 1; }

  const ushort4* pv = (const ushort4*)(part + (size_t)P * (NCH * 8));
  for (int c = 0; c < NCH * 2; ++c) {        // 64 x ushort4 = 256 candidates
    ushort4 v = pv[c];
    int j0 = v.x & (NRr - 1), j1 = v.y & (NRr - 1);
    int j2 = v.z & (NRr - 1), j3 = v.w & (NRr - 1);
    insert_lex(d2f(px, py, pz, sp, refbase[j0]), j0, dist, id);
    insert_lex(d2f(px, py, pz, sp, refbase[j1]), j1, dist, id);
    insert_lex(d2f(px, py, pz, sp, refbase[j2]), j2, dist, id);
    insert_lex(d2f(px, py, pz, sp, refbase[j3]), j3, dist, id);
  }
  #pragma unroll
  for (int k = 0; k < 8; ++k) idx[(size_t)P*8 + k] = id[k] & (NRr - 1);
}

// ------- fold Wout@Wo@Wv -> A [512,256] bf16, bbig f32 (8 rows/block) -------
__global__ __launch_bounds__(256) void k_combine(const float* __restrict__ Wv,
    const float* __restrict__ bv, const float* __restrict__ Wo,
    const float* __restrict__ bo, const float* __restrict__ Wout,
    uint16_t* __restrict__ Aw, float* __restrict__ bbig) {
  __shared__ float M8[8][256];
  __shared__ float red[256];
  int e0 = blockIdx.x * 8;   // 0..511 in groups of 8
  int t  = threadIdx.x;      // 0..255

  float acc8[8];
  #pragma unroll
  for (int e = 0; e < 8; ++e) acc8[e] = 0.f;
  for (int d = 0; d < 256; ++d) {
    float wo = Wo[(size_t)d*256 + t];
    #pragma unroll
    for (int e = 0; e < 8; ++e)
      acc8[e] = fmaf(Wout[(size_t)(e0+e)*256 + d], wo, acc8[e]);
  }
  #pragma unroll
  for (int e = 0; e < 8; ++e) M8[e][t] = acc8[e];
  __syncthreads();

  float a8[8];
  #pragma unroll
  for (int e = 0; e < 8; ++e) a8[e] = 0.f;
  for (int c = 0; c < 256; ++c) {
    float wv = Wv[(size_t)c*256 + t];
    #pragma unroll
    for (int e = 0; e < 8; ++e)
      a8[e] = fmaf(M8[e][c], wv, a8[e]);
  }
  #pragma unroll
  for (int e = 0; e < 8; ++e) Aw[(size_t)(e0+e)*256 + t] = f2bf(a8[e]);

  for (int e = 0; e < 8; ++e) {
    red[t] = fmaf(M8[e][t], bv[t], Wout[(size_t)(e0+e)*256 + t] * bo[t]);
    __syncthreads();
    for (int s2 = 128; s2 > 0; s2 >>= 1) {
      if (t < s2) red[t] += red[t + s2];
      __syncthreads();
    }
    if (t == 0) bbig[e0+e] = red[0];
    __syncthreads();
  }
}

// ---------------- attention: one wave per pred point ------------------------
__global__ __launch_bounds__(256) void k_attn(const float* __restrict__ feat_q,
    const float* __restrict__ feat_k, const float* __restrict__ feat_v,
    const int* __restrict__ idx, uint16_t* __restrict__ g) {
  int wave = threadIdx.x >> 6;
  int lane = threadIdx.x & 63;
  int P = blockIdx.x * 4 + wave;     // 0..16383
  int b = P >> 13;
  const int* ip = idx + (size_t)P * 8;
  int nb[8];
  #pragma unroll
  for (int k = 0; k < 8; ++k) nb[k] = ip[k] & (NRr - 1);

  float4 qv = *(const float4*)(feat_q + (size_t)P*NC + lane*4);
  const float* kb = feat_k + (size_t)b * NRr * NC;
  const float* vb = feat_v + (size_t)b * NRr * NC;

  float s[8];
  #pragma unroll
  for (int k = 0; k < 8; ++k) {
    float4 kv = *(const float4*)(kb + (size_t)nb[k]*NC + lane*4);
    float p = qv.x * kv.x;
    p = fmaf(qv.y, kv.y, p);
    p = fmaf(qv.z, kv.z, p);
    p = fmaf(qv.w, kv.w, p);
    s[k] = p;
  }
  #pragma unroll
  for (int k = 0; k < 8; ++k) {
    float v = s[k];
    #pragma unroll
    for (int m = 1; m < 64; m <<= 1) v += __shfl_xor(v, m, 64);
    s[k] = v * 0.0625f;   // / sqrt(256), exact
  }
  float mx = s[0];
  #pragma unroll
  for (int k = 1; k < 8; ++k) mx = fmaxf(mx, s[k]);
  float e[8], sum = 0.f;
  #pragma unroll
  for (int k = 0; k < 8; ++k) { e[k] = expf(s[k] - mx); sum += e[k]; }
  float inv = 1.0f / sum;

  float g0 = 0.f, g1 = 0.f, g2 = 0.f, g3 = 0.f;
  #pragma unroll
  for (int k = 0; k < 8; ++k) {
    float4 vv = *(const float4*)(vb + (size_t)nb[k]*NC + lane*4);
    float w = e[k] * inv;
    g0 = fmaf(w, vv.x, g0);
    g1 = fmaf(w, vv.y, g1);
    g2 = fmaf(w, vv.z, g2);
    g3 = fmaf(w, vv.w, g3);
  }
  uint32_t p0 = ((uint32_t)f2bf(g1) << 16) | f2bf(g0);
  uint32_t p1 = ((uint32_t)f2bf(g3) << 16) | f2bf(g2);
  *(uint2*)(g + (size_t)P*NC + lane*4) = make_uint2(p0, p1);
}

// ---------------- zero-fill ref halves of output (runs LAST) ----------------
__global__ void k_zero(float4* __restrict__ o) {
  int i = blockIdx.x * 256 + threadIdx.x;  // 0 .. 2097151
  int b = i >> 20;                         // region 0 or 1
  int r = i & 1048575;                     // 1M float4 per 16MB region
  o[(size_t)b * 2097152 + r] = make_float4(0.f, 0.f, 0.f, 0.f);
}

// ---------------- final GEMM: g[16384,256]bf16 @ A^T + bbig -> f32 ----------
__global__ __launch_bounds__(256) void k_gemm(const uint16_t* __restrict__ g,
    const uint16_t* __restrict__ Aw, const float* __restrict__ bbig,
    float* __restrict__ outp) {
  // LDS stride 136 (272B): 16B-aligned rows, 4-bank shift/row => conflict-free
  __shared__ __align__(16) uint16_t sA[64 * 136];
  __shared__ __align__(16) uint16_t sB[64 * 136];
  int t = threadIdx.x;
  int lane = t & 63, wave = t >> 6;
  int wm = (wave >> 1) * 32, wn = (wave & 1) * 32;
  int q = lane >> 4, rr = lane & 15;
  int bm = blockIdx.x;   // 0..255 (M tiles of 64)
  int bn = blockIdx.y;   // 0..7   (N tiles of 64)
  f32x4 zero = {0.f, 0.f, 0.f, 0.f};
  f32x4 acc[2][2] = {{zero, zero}, {zero, zero}};

  for (int ph = 0; ph < 2; ++ph) {      // K = 256 in two 128 phases
    #pragma unroll
    for (int i = 0; i < 4; ++i) {
      int cc  = t + i * 256;            // 0..1023 chunks of 8 bf16
      int row = cc >> 4;                // 16 chunks per row
      int col = (cc & 15) << 3;
      uint4 da = *(const uint4*)(g  + ((size_t)(bm*64 + row))*NC + ph*128 + col);
      *(uint4*)(&sA[row*136 + col]) = da;
      uint4 db = *(const uint4*)(Aw + ((size_t)(bn*64 + row))*NC + ph*128 + col);
      *(uint4*)(&sB[row*136 + col]) = db;
    }
    __syncthreads();
    #pragma unroll
    for (int kk = 0; kk < 4; ++kk) {
      int ko = kk*32 + q*8;
      bf16x8 a0 = *(const bf16x8*)(&sA[(wm      + rr)*136 + ko]);
      bf16x8 a1 = *(const bf16x8*)(&sA[(wm + 16 + rr)*136 + ko]);
      bf16x8 b0 = *(const bf16x8*)(&sB[(wn      + rr)*136 + ko]);
      bf16x8 b1 = *(const bf16x8*)(&sB[(wn + 16 + rr)*136 + ko]);
      acc[0][0] = __builtin_amdgcn_mfma_f32_16x16x32_bf16(a0, b0, acc[0][0], 0, 0, 0);
      acc[0][1] = __builtin_amdgcn_mfma_f32_16x16x32_bf16(a0, b1, acc[0][1], 0, 0, 0);
      acc[1][0] = __builtin_amdgcn_mfma_f32_16x16x32_bf16(a1, b0, acc[1][0], 0, 0, 0);
      acc[1][1] = __builtin_amdgcn_mfma_f32_16x16x32_bf16(a1, b1, acc[1][1], 0, 0, 0);
    }
    __syncthreads();
  }
  #pragma unroll
  for (int j = 0; j < 2; ++j) {
    int col = bn*64 + wn + j*16 + rr;
    float bias = bbig[col];
    #pragma unroll
    for (int i = 0; i < 2; ++i) {
      #pragma unroll
      for (int r = 0; r < 4; ++r) {
        int row = bm*64 + wm + i*16 + q*4 + r;   // C/D: col=lane&15, row=(lane>>4)*4+reg
        float v = acc[i][j][r] + bias;
        int bb = row >> 13, p = row & 8191;
        outp[((size_t)(bb*16384 + 8192 + p))*512 + col] = v;
      }
    }
  }
}

extern "C" void kernel_launch(void* const* d_in, const int* in_sizes, int n_in,
                              void* d_out, int out_size, void* d_ws, size_t ws_size,
                              hipStream_t stream) {
  const float* xyz_ref  = (const float*)d_in[0];
  const float* xyz_pred = (const float*)d_in[1];
  const float* feat_k   = (const float*)d_in[2];
  const float* feat_q   = (const float*)d_in[3];
  const float* feat_v   = (const float*)d_in[4];
  const float* Wv       = (const float*)d_in[5];
  const float* bv       = (const float*)d_in[6];
  const float* Wo       = (const float*)d_in[7];
  const float* bo       = (const float*)d_in[8];
  const float* Wout     = (const float*)d_in[9];
  float* outp = (float*)d_out;

  // ALL scratch inside d_out's dead ref-half regions (f32 output, 64MB):
  char* ob = (char*)d_out;
  uint16_t* g    = (uint16_t*)ob;                    // [0, 8M)    bf16 16384x256
  float4*   ref4 = (float4*)(ob + 8388608);          // [8M, 8.25M)
  int*      idx  = (int*)(ob + 8650752);             // [8.25M, 8.75M)
  uint16_t* Aw   = (uint16_t*)(ob + 9175040);        // [8.75M, 9M)
  float*    bbig = (float*)(ob + 9437184);           // [9M, +2K)
  uint16_t* part = (uint16_t*)(ob + 33554432);       // [32M, 40M)  8 MB u16

  k_prep   <<<256,  64,  0, stream>>>(xyz_ref, ref4);
  k_knn    <<<2048, 256, 0, stream>>>(xyz_pred, ref4, part);
  k_merge  <<<256,  64,  0, stream>>>(part, xyz_pred, ref4, idx);
  k_combine<<<64,   256, 0, stream>>>(Wv, bv, Wo, bo, Wout, Aw, bbig);
  k_attn   <<<4096, 256, 0, stream>>>(feat_q, feat_k, feat_v, idx, g);
  k_gemm   <<<dim3(256, 8), 256, 0, stream>>>(g, Aw, bbig, outp);
  k_zero   <<<8192, 256, 0, stream>>>((float4*)outp);
}

// Round 9
// 413.439 us; speedup vs baseline: 1.0911x; 1.0570x over previous
//
#include <hip/hip_runtime.h>
#include <stdint.h>

// CrossAttn: B=2, Nr=Np=8192, C=256, K=8. ALL I/O float32.
// R19: FUSE k_combine into k_knn. k_combine depends on nothing upstream and
// feeds only k_gemm (2 launches later), yet ran serially on 64 blocks (1/4 of
// CUs, ~1 wave/SIMD, two serial 256-iter fma loops + 8 barrier reductions):
// est 25-45us of pure serial tail. Now blocks 0..63 of the knn launch run the
// combine path (byte-identical math), blocks 64..2111 run knn (task id
// shifted). LDS is a manual union (combine M8 8K+red 1K overlays knn 16K
// sref; paths never coexist per block) -> knn footprint unchanged. knn body
// = R18 verbatim (readlane broadcast + med3 dual chains, 148us, passing).
// Also a probe: k_combine vanishes from the timeline -> its delta measures
// its true serial cost; may surface k_attn/k_gemm in top-5.
// Scratch: NO d_ws. All inside d_out dead ref-half regions:
//   g 8MB [0,8M); ref4 [8M,..); idx [8.25M,..); Aw [8.75M,..); bbig [9M,..);
//   part u16 8MB [32M,40M).
// k_gemm writes pred halves [16M,32M)+[48M,64M); k_zero zeroes ref halves LAST.

#define NRr 8192
#define NPp 8192
#define NC  256
#define NK  8
#define NCH   32     // ref chunks
#define CHUNK 256    // refs per chunk

typedef short bf16x8 __attribute__((ext_vector_type(8)));
typedef float f32x4  __attribute__((ext_vector_type(4)));

__device__ __forceinline__ uint16_t f2bf(float f) {
  uint32_t u = __float_as_uint(f);
  return (uint16_t)((u + 0x7fffu + ((u >> 16) & 1u)) >> 16);
}

// Exact np-f32 d2: rounded products, sequential adds, (sp+sr) - (dot+dot).
// Used by k_knn (all passes) and k_merge so recomputation is bitwise identical.
__device__ __forceinline__ float d2f(float px, float py, float pz, float sp, float4 r) {
  float m0 = __fmul_rn(px, r.x), m1 = __fmul_rn(py, r.y), m2 = __fmul_rn(pz, r.z);
  float dot = __fadd_rn(__fadd_rn(m0, m1), m2);
  return __fsub_rn(__fadd_rn(sp, r.w), __fadd_rn(dot, dot));
}

// ---------------- prep: ref coords + |r|^2 (literal np rounding) ------------
__global__ __launch_bounds__(64) void k_prep(const float* __restrict__ xyz_ref,
                                             float4* __restrict__ ref4) {
  int i = blockIdx.x * 64 + threadIdx.x;       // 0 .. 2*NR-1 (256 blocks x 64)
  if (i >= 2 * NRr) return;
  float x = xyz_ref[i*3+0];
  float y = xyz_ref[i*3+1];
  float z = xyz_ref[i*3+2];
  float n = __fadd_rn(__fadd_rn(__fmul_rn(x,x), __fmul_rn(y,y)), __fmul_rn(z,z));
  ref4[i] = make_float4(x, y, z, n);
}

// sorted-8 insert, strict < on d2 (scan order ascending idx => lex-stable)
__device__ __forceinline__ void insert8(float d2, int j, float (&dist)[8], int (&id)[8]) {
  if (d2 < dist[7]) {
    #pragma unroll
    for (int k = 7; k >= 1; --k) {
      bool sh = d2 < dist[k-1];
      bool pl = d2 < dist[k];
      float nd = sh ? dist[k-1] : (pl ? d2 : dist[k]);
      int   ni = sh ? id[k-1]   : (pl ? j  : id[k]);
      dist[k] = nd; id[k] = ni;
    }
    if (d2 < dist[0]) { dist[0] = d2; id[0] = j; }
  }
}

// broadcast lane L's candidate float4 (wave-uniform L) into all lanes
__device__ __forceinline__ float4 bcast4(uint32_t cx, uint32_t cy,
                                         uint32_t cz, uint32_t cw, int L) {
  return make_float4(__uint_as_float(__builtin_amdgcn_readlane(cx, L)),
                     __uint_as_float(__builtin_amdgcn_readlane(cy, L)),
                     __uint_as_float(__builtin_amdgcn_readlane(cz, L)),
                     __uint_as_float(__builtin_amdgcn_readlane(cw, L)));
}

// one 64-candidate block: readlane broadcast, dual 4-chains (med3), per-half
// mask + immediate finalize (ascending j: bq asc, half asc, ctz asc)
__device__ __forceinline__ void kblock(float4 rc, int bq,
    float px, float py, float pz, float sp,
    float &a0, float &a1, float &a2, float &a3,
    float &g0, float &g1, float &g2, float &g3,
    float (&dist)[8], int (&id)[8], const float4* srefw) {
  uint32_t cx = __float_as_uint(rc.x), cy = __float_as_uint(rc.y);
  uint32_t cz = __float_as_uint(rc.z), cw = __float_as_uint(rc.w);
  #pragma unroll
  for (int half = 0; half < 2; ++half) {
    uint32_t mm = 0;
    #pragma unroll 4
    for (int t = 0; t < 32; t += 2) {
      int L0 = half*32 + t;
      float4 r0 = bcast4(cx, cy, cz, cw, L0);
      float4 r1 = bcast4(cx, cy, cz, cw, L0 + 1);
      float d0 = d2f(px, py, pz, sp, r0);
      float d1 = d2f(px, py, pz, sp, r1);
      // chain A <- even candidate; med3(x,lo,hi) == sorted-insert shift
      a3 = __builtin_amdgcn_fmed3f(d0, a2, a3);
      a2 = __builtin_amdgcn_fmed3f(d0, a1, a2);
      a1 = __builtin_amdgcn_fmed3f(d0, a0, a1);
      a0 = fminf(d0, a0);
      // chain G <- odd candidate
      g3 = __builtin_amdgcn_fmed3f(d1, g2, g3);
      g2 = __builtin_amdgcn_fmed3f(d1, g1, g2);
      g1 = __builtin_amdgcn_fmed3f(d1, g0, g1);
      g0 = fminf(d1, g0);
      float tau = fmaxf(a3, g3);               // >= running 8th >= final T8
      mm |= (uint32_t)(d0 <= tau) << t;
      mm |= (uint32_t)(d1 <= tau) << (t + 1);
    }
    // finalize this half's survivors (ascending j, strict <)
    int jb = bq*64 + half*32;
    while (mm) {
      int bit = __builtin_ctz(mm); mm &= mm - 1;
      int j = jb + bit;
      float dd = d2f(px, py, pz, sp, srefw[j]);
      insert8(dd, j, dist, id);
    }
  }
}

// ---- FUSED: blocks 0..63 = combine (Wout@Wo@Wv fold); 64..2111 = KNN -------
// KNN: 4 independent single-wave bodies per 256-thr block; wave-task =
// (blockIdx-64)*4 + wave; ch = task & 31; point-group = task >> 5. Each wave
// stages its OWN LDS segment; no barrier, no cross-wave coupling.
// Combine: byte-identical to the old k_combine (e0 = blockIdx*8).
// LDS union: knn uses [0,16K) as float4 sref[4][256]; combine uses [0,8K) as
// M8[8][256] + [8K,9K) as red[256]. Paths never coexist in one block.
__global__ __launch_bounds__(256, 6) void k_knn(const float* __restrict__ xyz_pred,
                                                const float4* __restrict__ ref4,
                                                uint16_t* __restrict__ part,
                                                const float* __restrict__ Wv,
                                                const float* __restrict__ bv,
                                                const float* __restrict__ Wo,
                                                const float* __restrict__ bo,
                                                const float* __restrict__ Wout,
                                                uint16_t* __restrict__ Aw,
                                                float* __restrict__ bbig) {
  __shared__ __align__(16) char smem[16384];

  if (blockIdx.x < 64) {
    // ================= combine path (verbatim k_combine) ===================
    float (*M8)[256] = (float (*)[256])smem;         // 8 KB
    float* red = (float*)(smem + 8192);              // 1 KB
    int e0 = blockIdx.x * 8;   // 0..511 in groups of 8
    int t  = threadIdx.x;      // 0..255

    float acc8[8];
    #pragma unroll
    for (int e = 0; e < 8; ++e) acc8[e] = 0.f;
    for (int d = 0; d < 256; ++d) {
      float wo = Wo[(size_t)d*256 + t];
      #pragma unroll
      for (int e = 0; e < 8; ++e)
        acc8[e] = fmaf(Wout[(size_t)(e0+e)*256 + d], wo, acc8[e]);
    }
    #pragma unroll
    for (int e = 0; e < 8; ++e) M8[e][t] = acc8[e];
    __syncthreads();

    float a8[8];
    #pragma unroll
    for (int e = 0; e < 8; ++e) a8[e] = 0.f;
    for (int c = 0; c < 256; ++c) {
      float wv = Wv[(size_t)c*256 + t];
      #pragma unroll
      for (int e = 0; e < 8; ++e)
        a8[e] = fmaf(M8[e][c], wv, a8[e]);
    }
    #pragma unroll
    for (int e = 0; e < 8; ++e) Aw[(size_t)(e0+e)*256 + t] = f2bf(a8[e]);

    for (int e = 0; e < 8; ++e) {
      red[t] = fmaf(M8[e][t], bv[t], Wout[(size_t)(e0+e)*256 + t] * bo[t]);
      __syncthreads();
      for (int s2 = 128; s2 > 0; s2 >>= 1) {
        if (t < s2) red[t] += red[t + s2];
        __syncthreads();
      }
      if (t == 0) bbig[e0+e] = red[0];
      __syncthreads();
    }
    return;
  }

  // ======================== knn path (R18 verbatim) ========================
  float4* sref = (float4*)smem;                      // 16 KB (finalize only)
  int wave = threadIdx.x >> 6;
  int lane = threadIdx.x & 63;
  int task = (blockIdx.x - 64) * 4 + wave;     // 0..8191
  int ch   = task & (NCH - 1);                 // 0..31
  int P    = (task >> 5) * 64 + lane;          // global point 0..16383
  int b    = P >> 13;

  float px = xyz_pred[P*3+0];
  float py = xyz_pred[P*3+1];
  float pz = xyz_pred[P*3+2];
  float sp = __fadd_rn(__fadd_rn(__fmul_rn(px,px), __fmul_rn(py,py)), __fmul_rn(pz,pz));

  const float4* refbase = ref4 + (size_t)b * NRr;
  int rbase = ch * CHUNK;

  // each lane owns candidate (bq*64 + lane); mirror to LDS for finalize reads
  float4* srefw = sref + wave * CHUNK;
  float4 rc0 = refbase[rbase +   0 + lane];
  float4 rc1 = refbase[rbase +  64 + lane];
  float4 rc2 = refbase[rbase + 128 + lane];
  float4 rc3 = refbase[rbase + 192 + lane];
  srefw[  0 + lane] = rc0;
  srefw[ 64 + lane] = rc1;
  srefw[128 + lane] = rc2;
  srefw[192 + lane] = rc3;
  // no __syncthreads: in-wave ds_write -> ds_read ordering via lgkmcnt

  float a0 = 3.4e38f, a1 = 3.4e38f, a2 = 3.4e38f, a3 = 3.4e38f;
  float g0 = 3.4e38f, g1 = 3.4e38f, g2 = 3.4e38f, g3 = 3.4e38f;
  float dist[8]; int id[8];
  #pragma unroll
  for (int k = 0; k < 8; ++k) { dist[k] = 3.4e38f; id[k] = 0; }

  kblock(rc0, 0, px, py, pz, sp, a0, a1, a2, a3, g0, g1, g2, g3, dist, id, srefw);
  kblock(rc1, 1, px, py, pz, sp, a0, a1, a2, a3, g0, g1, g2, g3, dist, id, srefw);
  kblock(rc2, 2, px, py, pz, sp, a0, a1, a2, a3, g0, g1, g2, g3, dist, id, srefw);
  kblock(rc3, 3, px, py, pz, sp, a0, a1, a2, a3, g0, g1, g2, g3, dist, id, srefw);

  uint16_t* pp = part + ((size_t)P * NCH + ch) * 8;
  #pragma unroll
  for (int k = 0; k < 8; ++k)
    pp[k] = (uint16_t)((rbase + id[k]) & (NRr - 1));
}

// lex (d2, idx) insert for the merge of the chunk partials
__device__ __forceinline__ void insert_lex(float d2, int j, float (&dist)[8], int (&id)[8]) {
  bool b7 = (d2 < dist[7]) || (d2 == dist[7] && j < id[7]);
  if (b7) {
    #pragma unroll
    for (int k = 7; k >= 1; --k) {
      bool sh = (d2 < dist[k-1]) || (d2 == dist[k-1] && j < id[k-1]);
      bool pl = (d2 < dist[k])   || (d2 == dist[k]   && j < id[k]);
      float nd = sh ? dist[k-1] : (pl ? d2 : dist[k]);
      int   ni = sh ? id[k-1]   : (pl ? j  : id[k]);
      dist[k] = nd; id[k] = ni;
    }
    bool p0 = (d2 < dist[0]) || (d2 == dist[0] && j < id[0]);
    if (p0) { dist[0] = d2; id[0] = j; }
  }
}

// merge: recompute d2 exactly from ref4 (d2f) for the 256 u16 candidates
__global__ __launch_bounds__(64) void k_merge(const uint16_t* __restrict__ part,
                                              const float* __restrict__ xyz_pred,
                                              const float4* __restrict__ ref4,
                                              int* __restrict__ idx) {
  int P = blockIdx.x * 64 + threadIdx.x;    // 0..16383 (256 blocks x 64)
  int b = P >> 13;
  float px = xyz_pred[P*3+0];
  float py = xyz_pred[P*3+1];
  float pz = xyz_pred[P*3+2];
  float sp = __fadd_rn(__fadd_rn(__fmul_rn(px,px), __fmul_rn(py,py)), __fmul_rn(pz,pz));
  const float4* refbase = ref4 + (size_t)b * NRr;

  float dist[8]; int id[8];
  #pragma unroll
  for (int k = 0; k < 8; ++k) { dist[k] = 3.4e38f; id[k] = NRr - 1; }

  const ushort4* pv = (const ushort4*)(part + (size_t)P * (NCH * 8));
  for (int c = 0; c < NCH * 2; ++c) {        // 64 x ushort4 = 256 candidates
    ushort4 v = pv[c];
    int j0 = v.x & (NRr - 1), j1 = v.y & (NRr - 1);
    int j2 = v.z & (NRr - 1), j3 = v.w & (NRr - 1);
    insert_lex(d2f(px, py, pz, sp, refbase[j0]), j0, dist, id);
    insert_lex(d2f(px, py, pz, sp, refbase[j1]), j1, dist, id);
    insert_lex(d2f(px, py, pz, sp, refbase[j2]), j2, dist, id);
    insert_lex(d2f(px, py, pz, sp, refbase[j3]), j3, dist, id);
  }
  #pragma unroll
  for (int k = 0; k < 8; ++k) idx[(size_t)P*8 + k] = id[k] & (NRr - 1);
}

// ---------------- attention: one wave per pred point ------------------------
__global__ __launch_bounds__(256) void k_attn(const float* __restrict__ feat_q,
    const float* __restrict__ feat_k, const float* __restrict__ feat_v,
    const int* __restrict__ idx, uint16_t* __restrict__ g) {
  int wave = threadIdx.x >> 6;
  int lane = threadIdx.x & 63;
  int P = blockIdx.x * 4 + wave;     // 0..16383
  int b = P >> 13;
  const int* ip = idx + (size_t)P * 8;
  int nb[8];
  #pragma unroll
  for (int k = 0; k < 8; ++k) nb[k] = ip[k] & (NRr - 1);

  float4 qv = *(const float4*)(feat_q + (size_t)P*NC + lane*4);
  const float* kb = feat_k + (size_t)b * NRr * NC;
  const float* vb = feat_v + (size_t)b * NRr * NC;

  float s[8];
  #pragma unroll
  for (int k = 0; k < 8; ++k) {
    float4 kv = *(const float4*)(kb + (size_t)nb[k]*NC + lane*4);
    float p = qv.x * kv.x;
    p = fmaf(qv.y, kv.y, p);
    p = fmaf(qv.z, kv.z, p);
    p = fmaf(qv.w, kv.w, p);
    s[k] = p;
  }
  #pragma unroll
  for (int k = 0; k < 8; ++k) {
    float v = s[k];
    #pragma unroll
    for (int m = 1; m < 64; m <<= 1) v += __shfl_xor(v, m, 64);
    s[k] = v * 0.0625f;   // / sqrt(256), exact
  }
  float mx = s[0];
  #pragma unroll
  for (int k = 1; k < 8; ++k) mx = fmaxf(mx, s[k]);
  float e[8], sum = 0.f;
  #pragma unroll
  for (int k = 0; k < 8; ++k) { e[k] = expf(s[k] - mx); sum += e[k]; }
  float inv = 1.0f / sum;

  float g0 = 0.f, g1 = 0.f, g2 = 0.f, g3 = 0.f;
  #pragma unroll
  for (int k = 0; k < 8; ++k) {
    float4 vv = *(const float4*)(vb + (size_t)nb[k]*NC + lane*4);
    float w = e[k] * inv;
    g0 = fmaf(w, vv.x, g0);
    g1 = fmaf(w, vv.y, g1);
    g2 = fmaf(w, vv.z, g2);
    g3 = fmaf(w, vv.w, g3);
  }
  uint32_t p0 = ((uint32_t)f2bf(g1) << 16) | f2bf(g0);
  uint32_t p1 = ((uint32_t)f2bf(g3) << 16) | f2bf(g2);
  *(uint2*)(g + (size_t)P*NC + lane*4) = make_uint2(p0, p1);
}

// ---------------- zero-fill ref halves of output (runs LAST) ----------------
__global__ void k_zero(float4* __restrict__ o) {
  int i = blockIdx.x * 256 + threadIdx.x;  // 0 .. 2097151
  int b = i >> 20;                         // region 0 or 1
  int r = i & 1048575;                     // 1M float4 per 16MB region
  o[(size_t)b * 2097152 + r] = make_float4(0.f, 0.f, 0.f, 0.f);
}

// ---------------- final GEMM: g[16384,256]bf16 @ A^T + bbig -> f32 ----------
__global__ __launch_bounds__(256) void k_gemm(const uint16_t* __restrict__ g,
    const uint16_t* __restrict__ Aw, const float* __restrict__ bbig,
    float* __restrict__ outp) {
  // LDS stride 136 (272B): 16B-aligned rows, 4-bank shift/row => conflict-free
  __shared__ __align__(16) uint16_t sA[64 * 136];
  __shared__ __align__(16) uint16_t sB[64 * 136];
  int t = threadIdx.x;
  int lane = t & 63, wave = t >> 6;
  int wm = (wave >> 1) * 32, wn = (wave & 1) * 32;
  int q = lane >> 4, rr = lane & 15;
  int bm = blockIdx.x;   // 0..255 (M tiles of 64)
  int bn = blockIdx.y;   // 0..7   (N tiles of 64)
  f32x4 zero = {0.f, 0.f, 0.f, 0.f};
  f32x4 acc[2][2] = {{zero, zero}, {zero, zero}};

  for (int ph = 0; ph < 2; ++ph) {      // K = 256 in two 128 phases
    #pragma unroll
    for (int i = 0; i < 4; ++i) {
      int cc  = t + i * 256;            // 0..1023 chunks of 8 bf16
      int row = cc >> 4;                // 16 chunks per row
      int col = (cc & 15) << 3;
      uint4 da = *(const uint4*)(g  + ((size_t)(bm*64 + row))*NC + ph*128 + col);
      *(uint4*)(&sA[row*136 + col]) = da;
      uint4 db = *(const uint4*)(Aw + ((size_t)(bn*64 + row))*NC + ph*128 + col);
      *(uint4*)(&sB[row*136 + col]) = db;
    }
    __syncthreads();
    #pragma unroll
    for (int kk = 0; kk < 4; ++kk) {
      int ko = kk*32 + q*8;
      bf16x8 a0 = *(const bf16x8*)(&sA[(wm      + rr)*136 + ko]);
      bf16x8 a1 = *(const bf16x8*)(&sA[(wm + 16 + rr)*136 + ko]);
      bf16x8 b0 = *(const bf16x8*)(&sB[(wn      + rr)*136 + ko]);
      bf16x8 b1 = *(const bf16x8*)(&sB[(wn + 16 + rr)*136 + ko]);
      acc[0][0] = __builtin_amdgcn_mfma_f32_16x16x32_bf16(a0, b0, acc[0][0], 0, 0, 0);
      acc[0][1] = __builtin_amdgcn_mfma_f32_16x16x32_bf16(a0, b1, acc[0][1], 0, 0, 0);
      acc[1][0] = __builtin_amdgcn_mfma_f32_16x16x32_bf16(a1, b0, acc[1][0], 0, 0, 0);
      acc[1][1] = __builtin_amdgcn_mfma_f32_16x16x32_bf16(a1, b1, acc[1][1], 0, 0, 0);
    }
    __syncthreads();
  }
  #pragma unroll
  for (int j = 0; j < 2; ++j) {
    int col = bn*64 + wn + j*16 + rr;
    float bias = bbig[col];
    #pragma unroll
    for (int i = 0; i < 2; ++i) {
      #pragma unroll
      for (int r = 0; r < 4; ++r) {
        int row = bm*64 + wm + i*16 + q*4 + r;   // C/D: col=lane&15, row=(lane>>4)*4+reg
        float v = acc[i][j][r] + bias;
        int bb = row >> 13, p = row & 8191;
        outp[((size_t)(bb*16384 + 8192 + p))*512 + col] = v;
      }
    }
  }
}

extern "C" void kernel_launch(void* const* d_in, const int* in_sizes, int n_in,
                              void* d_out, int out_size, void* d_ws, size_t ws_size,
                              hipStream_t stream) {
  const float* xyz_ref  = (const float*)d_in[0];
  const float* xyz_pred = (const float*)d_in[1];
  const float* feat_k   = (const float*)d_in[2];
  const float* feat_q   = (const float*)d_in[3];
  const float* feat_v   = (const float*)d_in[4];
  const float* Wv       = (const float*)d_in[5];
  const float* bv       = (const float*)d_in[6];
  const float* Wo       = (const float*)d_in[7];
  const float* bo       = (const float*)d_in[8];
  const float* Wout     = (const float*)d_in[9];
  float* outp = (float*)d_out;

  // ALL scratch inside d_out's dead ref-half regions (f32 output, 64MB):
  char* ob = (char*)d_out;
  uint16_t* g    = (uint16_t*)ob;                    // [0, 8M)    bf16 16384x256
  float4*   ref4 = (float4*)(ob + 8388608);          // [8M, 8.25M)
  int*      idx  = (int*)(ob + 8650752);             // [8.25M, 8.75M)
  uint16_t* Aw   = (uint16_t*)(ob + 9175040);        // [8.75M, 9M)
  float*    bbig = (float*)(ob + 9437184);           // [9M, +2K)
  uint16_t* part = (uint16_t*)(ob + 33554432);       // [32M, 40M)  8 MB u16

  k_prep   <<<256,  64,  0, stream>>>(xyz_ref, ref4);
  k_knn    <<<2112, 256, 0, stream>>>(xyz_pred, ref4, part,
                                      Wv, bv, Wo, bo, Wout, Aw, bbig);
  k_merge  <<<256,  64,  0, stream>>>(part, xyz_pred, ref4, idx);
  k_attn   <<<4096, 256, 0, stream>>>(feat_q, feat_k, feat_v, idx, g);
  k_gemm   <<<dim3(256, 8), 256, 0, stream>>>(g, Aw, bbig, outp);
  k_zero   <<<8192, 256, 0, stream>>>((float4*)outp);
}

// Round 10
// 353.653 us; speedup vs baseline: 1.2756x; 1.1691x over previous
//
#include <hip/hip_runtime.h>
#include <stdint.h>

// CrossAttn: B=2, Nr=Np=8192, C=256, K=8. ALL I/O float32.
// R20: bigger KNN chunks. The measured ~86 wave-instr/candidate vs ~21 static
// is dominated by per-chunk overheads that scale with CHUNK COUNT: (a) chain
// reset => survivor-inserts 32*(8+8ln32)~1150/point; (b) tau=INF warm-up (~8
// all-lane survivor bits per chunk). CHUNK 256->512 (NCH 32->16) halves both,
// halves part (8->4MB) and halves k_merge's candidate set (256->128). Grid:
// 1024 knn + 64 fused-combine blocks = 4.25/CU, all resident in one round at
// 32KB LDS (5 blocks/CU cap). Readlane dropped (suspected quarter-rate);
// back to LDS candidate reads; mask per 32-segment in ONE register with
// immediate finalize (no smask LDS). Superset proof per chunk unchanged;
// k_merge recomputes exact d2f + lex => final idx bit-identical to R10.
// Everything else unchanged from R19 (passing, 413us).
// Scratch: NO d_ws. All inside d_out dead ref-half regions:
//   g 8MB [0,8M); ref4 [8M,..); idx [8.25M,..); Aw [8.75M,..); bbig [9M,..);
//   part u16 4MB [32M,36M).
// k_gemm writes pred halves [16M,32M)+[48M,64M); k_zero zeroes ref halves LAST.

#define NRr 8192
#define NPp 8192
#define NC  256
#define NK  8
#define NCH   16     // ref chunks
#define CHUNK 512    // refs per chunk

typedef short bf16x8 __attribute__((ext_vector_type(8)));
typedef float f32x4  __attribute__((ext_vector_type(4)));

__device__ __forceinline__ uint16_t f2bf(float f) {
  uint32_t u = __float_as_uint(f);
  return (uint16_t)((u + 0x7fffu + ((u >> 16) & 1u)) >> 16);
}

// Exact np-f32 d2: rounded products, sequential adds, (sp+sr) - (dot+dot).
// Used by k_knn (all passes) and k_merge so recomputation is bitwise identical.
__device__ __forceinline__ float d2f(float px, float py, float pz, float sp, float4 r) {
  float m0 = __fmul_rn(px, r.x), m1 = __fmul_rn(py, r.y), m2 = __fmul_rn(pz, r.z);
  float dot = __fadd_rn(__fadd_rn(m0, m1), m2);
  return __fsub_rn(__fadd_rn(sp, r.w), __fadd_rn(dot, dot));
}

// ---------------- prep: ref coords + |r|^2 (literal np rounding) ------------
__global__ __launch_bounds__(64) void k_prep(const float* __restrict__ xyz_ref,
                                             float4* __restrict__ ref4) {
  int i = blockIdx.x * 64 + threadIdx.x;       // 0 .. 2*NR-1 (256 blocks x 64)
  if (i >= 2 * NRr) return;
  float x = xyz_ref[i*3+0];
  float y = xyz_ref[i*3+1];
  float z = xyz_ref[i*3+2];
  float n = __fadd_rn(__fadd_rn(__fmul_rn(x,x), __fmul_rn(y,y)), __fmul_rn(z,z));
  ref4[i] = make_float4(x, y, z, n);
}

// sorted-8 insert, strict < on d2 (scan order ascending idx => lex-stable)
__device__ __forceinline__ void insert8(float d2, int j, float (&dist)[8], int (&id)[8]) {
  if (d2 < dist[7]) {
    #pragma unroll
    for (int k = 7; k >= 1; --k) {
      bool sh = d2 < dist[k-1];
      bool pl = d2 < dist[k];
      float nd = sh ? dist[k-1] : (pl ? d2 : dist[k]);
      int   ni = sh ? id[k-1]   : (pl ? j  : id[k]);
      dist[k] = nd; id[k] = ni;
    }
    if (d2 < dist[0]) { dist[0] = d2; id[0] = j; }
  }
}

// ---- FUSED: blocks 0..63 = combine (Wout@Wo@Wv fold); 64..1087 = KNN -------
// KNN: 4 independent single-wave bodies per 256-thr block; wave-task =
// (blockIdx-64)*4 + wave; ch = task & 15; point-group = task >> 4. Each wave
// stages its OWN LDS segment; no barrier, no cross-wave coupling.
// Combine: byte-identical to the old k_combine (e0 = blockIdx*8).
// LDS union: knn uses [0,32K) as float4 sref[4][512]; combine uses [0,8K) as
// M8[8][256] + [8K,9K) as red[256]. Paths never coexist in one block.
__global__ __launch_bounds__(256, 5) void k_knn(const float* __restrict__ xyz_pred,
                                                const float4* __restrict__ ref4,
                                                uint16_t* __restrict__ part,
                                                const float* __restrict__ Wv,
                                                const float* __restrict__ bv,
                                                const float* __restrict__ Wo,
                                                const float* __restrict__ bo,
                                                const float* __restrict__ Wout,
                                                uint16_t* __restrict__ Aw,
                                                float* __restrict__ bbig) {
  __shared__ __align__(16) char smem[32768];

  if (blockIdx.x < 64) {
    // ================= combine path (verbatim k_combine) ===================
    float (*M8)[256] = (float (*)[256])smem;         // 8 KB
    float* red = (float*)(smem + 8192);              // 1 KB
    int e0 = blockIdx.x * 8;   // 0..511 in groups of 8
    int t  = threadIdx.x;      // 0..255

    float acc8[8];
    #pragma unroll
    for (int e = 0; e < 8; ++e) acc8[e] = 0.f;
    for (int d = 0; d < 256; ++d) {
      float wo = Wo[(size_t)d*256 + t];
      #pragma unroll
      for (int e = 0; e < 8; ++e)
        acc8[e] = fmaf(Wout[(size_t)(e0+e)*256 + d], wo, acc8[e]);
    }
    #pragma unroll
    for (int e = 0; e < 8; ++e) M8[e][t] = acc8[e];
    __syncthreads();

    float a8[8];
    #pragma unroll
    for (int e = 0; e < 8; ++e) a8[e] = 0.f;
    for (int c = 0; c < 256; ++c) {
      float wv = Wv[(size_t)c*256 + t];
      #pragma unroll
      for (int e = 0; e < 8; ++e)
        a8[e] = fmaf(M8[e][c], wv, a8[e]);
    }
    #pragma unroll
    for (int e = 0; e < 8; ++e) Aw[(size_t)(e0+e)*256 + t] = f2bf(a8[e]);

    for (int e = 0; e < 8; ++e) {
      red[t] = fmaf(M8[e][t], bv[t], Wout[(size_t)(e0+e)*256 + t] * bo[t]);
      __syncthreads();
      for (int s2 = 128; s2 > 0; s2 >>= 1) {
        if (t < s2) red[t] += red[t + s2];
        __syncthreads();
      }
      if (t == 0) bbig[e0+e] = red[0];
      __syncthreads();
    }
    return;
  }

  // ============================ knn path ===================================
  float4* sref = (float4*)smem;                      // 32 KB
  int wave = threadIdx.x >> 6;
  int lane = threadIdx.x & 63;
  int task = (blockIdx.x - 64) * 4 + wave;     // 0..4095
  int ch   = task & (NCH - 1);                 // 0..15
  int P    = (task >> 4) * 64 + lane;          // global point 0..16383
  int b    = P >> 13;

  float px = xyz_pred[P*3+0];
  float py = xyz_pred[P*3+1];
  float pz = xyz_pred[P*3+2];
  float sp = __fadd_rn(__fadd_rn(__fmul_rn(px,px), __fmul_rn(py,py)), __fmul_rn(pz,pz));

  const float4* refbase = ref4 + (size_t)b * NRr;
  int rbase = ch * CHUNK;
  float4* srefw = sref + wave * CHUNK;
  for (int j = lane; j < CHUNK; j += 64) srefw[j] = refbase[rbase + j];
  // no __syncthreads: in-wave ds_write -> ds_read ordering via lgkmcnt

  // dual 4-chains: a = top-4 of evens, g = top-4 of odds (ascending order)
  float a0 = 3.4e38f, a1 = 3.4e38f, a2 = 3.4e38f, a3 = 3.4e38f;
  float g0 = 3.4e38f, g1 = 3.4e38f, g2 = 3.4e38f, g3 = 3.4e38f;
  float dist[8]; int id[8];
  #pragma unroll
  for (int k = 0; k < 8; ++k) { dist[k] = 3.4e38f; id[k] = 0; }

  for (int s = 0; s < CHUNK / 32; ++s) {       // 16 segments x 32 candidates
    uint32_t mm = 0;
    int base = s * 32;
    #pragma unroll 2
    for (int jj = 0; jj < 32; jj += 2) {
      float d0 = d2f(px, py, pz, sp, srefw[base + jj]);
      float d1 = d2f(px, py, pz, sp, srefw[base + jj + 1]);
      // chain A <- even candidate; med3(x,lo,hi) == sorted-insert shift
      a3 = __builtin_amdgcn_fmed3f(d0, a2, a3);
      a2 = __builtin_amdgcn_fmed3f(d0, a1, a2);
      a1 = __builtin_amdgcn_fmed3f(d0, a0, a1);
      a0 = fminf(d0, a0);
      // chain G <- odd candidate
      g3 = __builtin_amdgcn_fmed3f(d1, g2, g3);
      g2 = __builtin_amdgcn_fmed3f(d1, g1, g2);
      g1 = __builtin_amdgcn_fmed3f(d1, g0, g1);
      g0 = fminf(d1, g0);
      float tau = fmaxf(a3, g3);               // >= running 8th >= final T8
      mm |= (uint32_t)(d0 <= tau) << jj;
      mm |= (uint32_t)(d1 <= tau) << (jj + 1);
    }
    // finalize this segment's survivors (ascending j, strict <)
    while (mm) {
      int bit = __builtin_ctz(mm); mm &= mm - 1;
      int j = base + bit;
      float dd = d2f(px, py, pz, sp, srefw[j]);
      insert8(dd, j, dist, id);
    }
  }

  uint16_t* pp = part + ((size_t)P * NCH + ch) * 8;
  #pragma unroll
  for (int k = 0; k < 8; ++k)
    pp[k] = (uint16_t)((rbase + id[k]) & (NRr - 1));
}

// lex (d2, idx) insert for the merge of the chunk partials
__device__ __forceinline__ void insert_lex(float d2, int j, float (&dist)[8], int (&id)[8]) {
  bool b7 = (d2 < dist[7]) || (d2 == dist[7] && j < id[7]);
  if (b7) {
    #pragma unroll
    for (int k = 7; k >= 1; --k) {
      bool sh = (d2 < dist[k-1]) || (d2 == dist[k-1] && j < id[k-1]);
      bool pl = (d2 < dist[k])   || (d2 == dist[k]   && j < id[k]);
      float nd = sh ? dist[k-1] : (pl ? d2 : dist[k]);
      int   ni = sh ? id[k-1]   : (pl ? j  : id[k]);
      dist[k] = nd; id[k] = ni;
    }
    bool p0 = (d2 < dist[0]) || (d2 == dist[0] && j < id[0]);
    if (p0) { dist[0] = d2; id[0] = j; }
  }
}

// merge: recompute d2 exactly from ref4 (d2f) for the 128 u16 candidates
__global__ __launch_bounds__(64) void k_merge(const uint16_t* __restrict__ part,
                                              const float* __restrict__ xyz_pred,
                                              const float4* __restrict__ ref4,
                                              int* __restrict__ idx) {
  int P = blockIdx.x * 64 + threadIdx.x;    // 0..16383 (256 blocks x 64)
  int b = P >> 13;
  float px = xyz_pred[P*3+0];
  float py = xyz_pred[P*3+1];
  float pz = xyz_pred[P*3+2];
  float sp = __fadd_rn(__fadd_rn(__fmul_rn(px,px), __fmul_rn(py,py)), __fmul_rn(pz,pz));
  const float4* refbase = ref4 + (size_t)b * NRr;

  float dist[8]; int id[8];
  #pragma unroll
  for (int k = 0; k < 8; ++k) { dist[k] = 3.4e38f; id[k] = NRr - 1; }

  const ushort4* pv = (const ushort4*)(part + (size_t)P * (NCH * 8));
  for (int c = 0; c < NCH * 2; ++c) {        // 32 x ushort4 = 128 candidates
    ushort4 v = pv[c];
    int j0 = v.x & (NRr - 1), j1 = v.y & (NRr - 1);
    int j2 = v.z & (NRr - 1), j3 = v.w & (NRr - 1);
    insert_lex(d2f(px, py, pz, sp, refbase[j0]), j0, dist, id);
    insert_lex(d2f(px, py, pz, sp, refbase[j1]), j1, dist, id);
    insert_lex(d2f(px, py, pz, sp, refbase[j2]), j2, dist, id);
    insert_lex(d2f(px, py, pz, sp, refbase[j3]), j3, dist, id);
  }
  #pragma unroll
  for (int k = 0; k < 8; ++k) idx[(size_t)P*8 + k] = id[k] & (NRr - 1);
}

// ---------------- attention: one wave per pred point ------------------------
__global__ __launch_bounds__(256) void k_attn(const float* __restrict__ feat_q,
    const float* __restrict__ feat_k, const float* __restrict__ feat_v,
    const int* __restrict__ idx, uint16_t* __restrict__ g) {
  int wave = threadIdx.x >> 6;
  int lane = threadIdx.x & 63;
  int P = blockIdx.x * 4 + wave;     // 0..16383
  int b = P >> 13;
  const int* ip = idx + (size_t)P * 8;
  int nb[8];
  #pragma unroll
  for (int k = 0; k < 8; ++k) nb[k] = ip[k] & (NRr - 1);

  float4 qv = *(const float4*)(feat_q + (size_t)P*NC + lane*4);
  const float* kb = feat_k + (size_t)b * NRr * NC;
  const float* vb = feat_v + (size_t)b * NRr * NC;

  float s[8];
  #pragma unroll
  for (int k = 0; k < 8; ++k) {
    float4 kv = *(const float4*)(kb + (size_t)nb[k]*NC + lane*4);
    float p = qv.x * kv.x;
    p = fmaf(qv.y, kv.y, p);
    p = fmaf(qv.z, kv.z, p);
    p = fmaf(qv.w, kv.w, p);
    s[k] = p;
  }
  #pragma unroll
  for (int k = 0; k < 8; ++k) {
    float v = s[k];
    #pragma unroll
    for (int m = 1; m < 64; m <<= 1) v += __shfl_xor(v, m, 64);
    s[k] = v * 0.0625f;   // / sqrt(256), exact
  }
  float mx = s[0];
  #pragma unroll
  for (int k = 1; k < 8; ++k) mx = fmaxf(mx, s[k]);
  float e[8], sum = 0.f;
  #pragma unroll
  for (int k = 0; k < 8; ++k) { e[k] = expf(s[k] - mx); sum += e[k]; }
  float inv = 1.0f / sum;

  float g0 = 0.f, g1 = 0.f, g2 = 0.f, g3 = 0.f;
  #pragma unroll
  for (int k = 0; k < 8; ++k) {
    float4 vv = *(const float4*)(vb + (size_t)nb[k]*NC + lane*4);
    float w = e[k] * inv;
    g0 = fmaf(w, vv.x, g0);
    g1 = fmaf(w, vv.y, g1);
    g2 = fmaf(w, vv.z, g2);
    g3 = fmaf(w, vv.w, g3);
  }
  uint32_t p0 = ((uint32_t)f2bf(g1) << 16) | f2bf(g0);
  uint32_t p1 = ((uint32_t)f2bf(g3) << 16) | f2bf(g2);
  *(uint2*)(g + (size_t)P*NC + lane*4) = make_uint2(p0, p1);
}

// ---------------- zero-fill ref halves of output (runs LAST) ----------------
__global__ void k_zero(float4* __restrict__ o) {
  int i = blockIdx.x * 256 + threadIdx.x;  // 0 .. 2097151
  int b = i >> 20;                         // region 0 or 1
  int r = i & 1048575;                     // 1M float4 per 16MB region
  o[(size_t)b * 2097152 + r] = make_float4(0.f, 0.f, 0.f, 0.f);
}

// ---------------- final GEMM: g[16384,256]bf16 @ A^T + bbig -> f32 ----------
__global__ __launch_bounds__(256) void k_gemm(const uint16_t* __restrict__ g,
    const uint16_t* __restrict__ Aw, const float* __restrict__ bbig,
    float* __restrict__ outp) {
  // LDS stride 136 (272B): 16B-aligned rows, 4-bank shift/row => conflict-free
  __shared__ __align__(16) uint16_t sA[64 * 136];
  __shared__ __align__(16) uint16_t sB[64 * 136];
  int t = threadIdx.x;
  int lane = t & 63, wave = t >> 6;
  int wm = (wave >> 1) * 32, wn = (wave & 1) * 32;
  int q = lane >> 4, rr = lane & 15;
  int bm = blockIdx.x;   // 0..255 (M tiles of 64)
  int bn = blockIdx.y;   // 0..7   (N tiles of 64)
  f32x4 zero = {0.f, 0.f, 0.f, 0.f};
  f32x4 acc[2][2] = {{zero, zero}, {zero, zero}};

  for (int ph = 0; ph < 2; ++ph) {      // K = 256 in two 128 phases
    #pragma unroll
    for (int i = 0; i < 4; ++i) {
      int cc  = t + i * 256;            // 0..1023 chunks of 8 bf16
      int row = cc >> 4;                // 16 chunks per row
      int col = (cc & 15) << 3;
      uint4 da = *(const uint4*)(g  + ((size_t)(bm*64 + row))*NC + ph*128 + col);
      *(uint4*)(&sA[row*136 + col]) = da;
      uint4 db = *(const uint4*)(Aw + ((size_t)(bn*64 + row))*NC + ph*128 + col);
      *(uint4*)(&sB[row*136 + col]) = db;
    }
    __syncthreads();
    #pragma unroll
    for (int kk = 0; kk < 4; ++kk) {
      int ko = kk*32 + q*8;
      bf16x8 a0 = *(const bf16x8*)(&sA[(wm      + rr)*136 + ko]);
      bf16x8 a1 = *(const bf16x8*)(&sA[(wm + 16 + rr)*136 + ko]);
      bf16x8 b0 = *(const bf16x8*)(&sB[(wn      + rr)*136 + ko]);
      bf16x8 b1 = *(const bf16x8*)(&sB[(wn + 16 + rr)*136 + ko]);
      acc[0][0] = __builtin_amdgcn_mfma_f32_16x16x32_bf16(a0, b0, acc[0][0], 0, 0, 0);
      acc[0][1] = __builtin_amdgcn_mfma_f32_16x16x32_bf16(a0, b1, acc[0][1], 0, 0, 0);
      acc[1][0] = __builtin_amdgcn_mfma_f32_16x16x32_bf16(a1, b0, acc[1][0], 0, 0, 0);
      acc[1][1] = __builtin_amdgcn_mfma_f32_16x16x32_bf16(a1, b1, acc[1][1], 0, 0, 0);
    }
    __syncthreads();
  }
  #pragma unroll
  for (int j = 0; j < 2; ++j) {
    int col = bn*64 + wn + j*16 + rr;
    float bias = bbig[col];
    #pragma unroll
    for (int i = 0; i < 2; ++i) {
      #pragma unroll
      for (int r = 0; r < 4; ++r) {
        int row = bm*64 + wm + i*16 + q*4 + r;   // C/D: col=lane&15, row=(lane>>4)*4+reg
        float v = acc[i][j][r] + bias;
        int bb = row >> 13, p = row & 8191;
        outp[((size_t)(bb*16384 + 8192 + p))*512 + col] = v;
      }
    }
  }
}

extern "C" void kernel_launch(void* const* d_in, const int* in_sizes, int n_in,
                              void* d_out, int out_size, void* d_ws, size_t ws_size,
                              hipStream_t stream) {
  const float* xyz_ref  = (const float*)d_in[0];
  const float* xyz_pred = (const float*)d_in[1];
  const float* feat_k   = (const float*)d_in[2];
  const float* feat_q   = (const float*)d_in[3];
  const float* feat_v   = (const float*)d_in[4];
  const float* Wv       = (const float*)d_in[5];
  const float* bv       = (const float*)d_in[6];
  const float* Wo       = (const float*)d_in[7];
  const float* bo       = (const float*)d_in[8];
  const float* Wout     = (const float*)d_in[9];
  float* outp = (float*)d_out;

  // ALL scratch inside d_out's dead ref-half regions (f32 output, 64MB):
  char* ob = (char*)d_out;
  uint16_t* g    = (uint16_t*)ob;                    // [0, 8M)    bf16 16384x256
  float4*   ref4 = (float4*)(ob + 8388608);          // [8M, 8.25M)
  int*      idx  = (int*)(ob + 8650752);             // [8.25M, 8.75M)
  uint16_t* Aw   = (uint16_t*)(ob + 9175040);        // [8.75M, 9M)
  float*    bbig = (float*)(ob + 9437184);           // [9M, +2K)
  uint16_t* part = (uint16_t*)(ob + 33554432);       // [32M, 36M)  4 MB u16

  k_prep   <<<256,  64,  0, stream>>>(xyz_ref, ref4);
  k_knn    <<<1088, 256, 0, stream>>>(xyz_pred, ref4, part,
                                      Wv, bv, Wo, bo, Wout, Aw, bbig);
  k_merge  <<<256,  64,  0, stream>>>(part, xyz_pred, ref4, idx);
  k_attn   <<<4096, 256, 0, stream>>>(feat_q, feat_k, feat_v, idx, g);
  k_gemm   <<<dim3(256, 8), 256, 0, stream>>>(g, Aw, bbig, outp);
  k_zero   <<<8192, 256, 0, stream>>>((float4*)outp);
}

// Round 11
// 292.273 us; speedup vs baseline: 1.5435x; 1.2100x over previous
//
#include <hip/hip_runtime.h>
#include <stdint.h>

// CrossAttn: B=2, Nr=Np=8192, C=256, K=8. ALL I/O float32.
// R21: ELIMINATE k_merge -- fused into k_attn wave-parallel. k_merge was 256
// waves on a 1024-SIMD chip (0.25 waves/SIMD, zero latency hiding), each
// thread doing 128 SERIAL gather+insert_lex rounds (~200cyc L2 + 80cyc VALU
// each) ~= 15-25us of near-idle machine + a launch gap. Now each k_attn wave
// (1 point) merges its own 128 candidates: 1 coalesced u32 load/lane (2 u16
// cands), exact d2f via 2 parallel gathers, monotone-u64 key
// (fkey(d2)<<32|j) -- fkey flips sign bit so float order == u32 order even
// for the d2<0 epsilon case -- then 8 rounds of wave butterfly u64-min with
// winner masking. Provably identical to insert_lex lex-(d2,j) top-8 (all j
// distinct: disjoint chunk ranges) => nb[] bit-identical => output
// bit-identical. ~350 VALU/wave, hidden under k_attn's gather latency (16K
// waves TLP). 6 launches -> 5. Everything else unchanged from R20 (353.7us).
// Scratch: NO d_ws. All inside d_out dead ref-half regions:
//   g 8MB [0,8M); ref4 [8M,..); Aw [8.75M,..); bbig [9M,..);
//   part u16 4MB [32M,36M).
// k_gemm writes pred halves [16M,32M)+[48M,64M); k_zero zeroes ref halves LAST.

#define NRr 8192
#define NPp 8192
#define NC  256
#define NK  8
#define NCH   16     // ref chunks
#define CHUNK 512    // refs per chunk

typedef short bf16x8 __attribute__((ext_vector_type(8)));
typedef float f32x4  __attribute__((ext_vector_type(4)));

__device__ __forceinline__ uint16_t f2bf(float f) {
  uint32_t u = __float_as_uint(f);
  return (uint16_t)((u + 0x7fffu + ((u >> 16) & 1u)) >> 16);
}

// Exact np-f32 d2: rounded products, sequential adds, (sp+sr) - (dot+dot).
// Used by k_knn and the fused merge so recomputation is bitwise identical.
__device__ __forceinline__ float d2f(float px, float py, float pz, float sp, float4 r) {
  float m0 = __fmul_rn(px, r.x), m1 = __fmul_rn(py, r.y), m2 = __fmul_rn(pz, r.z);
  float dot = __fadd_rn(__fadd_rn(m0, m1), m2);
  return __fsub_rn(__fadd_rn(sp, r.w), __fadd_rn(dot, dot));
}

// monotone float->u32 key: total order of floats == unsigned order of keys
__device__ __forceinline__ uint32_t fkey(float f) {
  uint32_t b = __float_as_uint(f);
  return (b & 0x80000000u) ? ~b : (b | 0x80000000u);
}

// ---------------- prep: ref coords + |r|^2 (literal np rounding) ------------
__global__ __launch_bounds__(64) void k_prep(const float* __restrict__ xyz_ref,
                                             float4* __restrict__ ref4) {
  int i = blockIdx.x * 64 + threadIdx.x;       // 0 .. 2*NR-1 (256 blocks x 64)
  if (i >= 2 * NRr) return;
  float x = xyz_ref[i*3+0];
  float y = xyz_ref[i*3+1];
  float z = xyz_ref[i*3+2];
  float n = __fadd_rn(__fadd_rn(__fmul_rn(x,x), __fmul_rn(y,y)), __fmul_rn(z,z));
  ref4[i] = make_float4(x, y, z, n);
}

// sorted-8 insert, strict < on d2 (scan order ascending idx => lex-stable)
__device__ __forceinline__ void insert8(float d2, int j, float (&dist)[8], int (&id)[8]) {
  if (d2 < dist[7]) {
    #pragma unroll
    for (int k = 7; k >= 1; --k) {
      bool sh = d2 < dist[k-1];
      bool pl = d2 < dist[k];
      float nd = sh ? dist[k-1] : (pl ? d2 : dist[k]);
      int   ni = sh ? id[k-1]   : (pl ? j  : id[k]);
      dist[k] = nd; id[k] = ni;
    }
    if (d2 < dist[0]) { dist[0] = d2; id[0] = j; }
  }
}

// ---- FUSED: blocks 0..63 = combine (Wout@Wo@Wv fold); 64..1087 = KNN -------
// KNN: 4 independent single-wave bodies per 256-thr block; wave-task =
// (blockIdx-64)*4 + wave; ch = task & 15; point-group = task >> 4. Each wave
// stages its OWN LDS segment; no barrier, no cross-wave coupling.
// Combine: byte-identical to the old k_combine (e0 = blockIdx*8).
// LDS union: knn uses [0,32K) as float4 sref[4][512]; combine uses [0,8K) as
// M8[8][256] + [8K,9K) as red[256]. Paths never coexist in one block.
__global__ __launch_bounds__(256, 5) void k_knn(const float* __restrict__ xyz_pred,
                                                const float4* __restrict__ ref4,
                                                uint16_t* __restrict__ part,
                                                const float* __restrict__ Wv,
                                                const float* __restrict__ bv,
                                                const float* __restrict__ Wo,
                                                const float* __restrict__ bo,
                                                const float* __restrict__ Wout,
                                                uint16_t* __restrict__ Aw,
                                                float* __restrict__ bbig) {
  __shared__ __align__(16) char smem[32768];

  if (blockIdx.x < 64) {
    // ================= combine path (verbatim k_combine) ===================
    float (*M8)[256] = (float (*)[256])smem;         // 8 KB
    float* red = (float*)(smem + 8192);              // 1 KB
    int e0 = blockIdx.x * 8;   // 0..511 in groups of 8
    int t  = threadIdx.x;      // 0..255

    float acc8[8];
    #pragma unroll
    for (int e = 0; e < 8; ++e) acc8[e] = 0.f;
    for (int d = 0; d < 256; ++d) {
      float wo = Wo[(size_t)d*256 + t];
      #pragma unroll
      for (int e = 0; e < 8; ++e)
        acc8[e] = fmaf(Wout[(size_t)(e0+e)*256 + d], wo, acc8[e]);
    }
    #pragma unroll
    for (int e = 0; e < 8; ++e) M8[e][t] = acc8[e];
    __syncthreads();

    float a8[8];
    #pragma unroll
    for (int e = 0; e < 8; ++e) a8[e] = 0.f;
    for (int c = 0; c < 256; ++c) {
      float wv = Wv[(size_t)c*256 + t];
      #pragma unroll
      for (int e = 0; e < 8; ++e)
        a8[e] = fmaf(M8[e][c], wv, a8[e]);
    }
    #pragma unroll
    for (int e = 0; e < 8; ++e) Aw[(size_t)(e0+e)*256 + t] = f2bf(a8[e]);

    for (int e = 0; e < 8; ++e) {
      red[t] = fmaf(M8[e][t], bv[t], Wout[(size_t)(e0+e)*256 + t] * bo[t]);
      __syncthreads();
      for (int s2 = 128; s2 > 0; s2 >>= 1) {
        if (t < s2) red[t] += red[t + s2];
        __syncthreads();
      }
      if (t == 0) bbig[e0+e] = red[0];
      __syncthreads();
    }
    return;
  }

  // ============================ knn path ===================================
  float4* sref = (float4*)smem;                      // 32 KB
  int wave = threadIdx.x >> 6;
  int lane = threadIdx.x & 63;
  int task = (blockIdx.x - 64) * 4 + wave;     // 0..4095
  int ch   = task & (NCH - 1);                 // 0..15
  int P    = (task >> 4) * 64 + lane;          // global point 0..16383
  int b    = P >> 13;

  float px = xyz_pred[P*3+0];
  float py = xyz_pred[P*3+1];
  float pz = xyz_pred[P*3+2];
  float sp = __fadd_rn(__fadd_rn(__fmul_rn(px,px), __fmul_rn(py,py)), __fmul_rn(pz,pz));

  const float4* refbase = ref4 + (size_t)b * NRr;
  int rbase = ch * CHUNK;
  float4* srefw = sref + wave * CHUNK;
  for (int j = lane; j < CHUNK; j += 64) srefw[j] = refbase[rbase + j];
  // no __syncthreads: in-wave ds_write -> ds_read ordering via lgkmcnt

  // dual 4-chains: a = top-4 of evens, g = top-4 of odds (ascending order)
  float a0 = 3.4e38f, a1 = 3.4e38f, a2 = 3.4e38f, a3 = 3.4e38f;
  float g0 = 3.4e38f, g1 = 3.4e38f, g2 = 3.4e38f, g3 = 3.4e38f;
  float dist[8]; int id[8];
  #pragma unroll
  for (int k = 0; k < 8; ++k) { dist[k] = 3.4e38f; id[k] = 0; }

  for (int s = 0; s < CHUNK / 32; ++s) {       // 16 segments x 32 candidates
    uint32_t mm = 0;
    int base = s * 32;
    #pragma unroll 2
    for (int jj = 0; jj < 32; jj += 2) {
      float d0 = d2f(px, py, pz, sp, srefw[base + jj]);
      float d1 = d2f(px, py, pz, sp, srefw[base + jj + 1]);
      // chain A <- even candidate; med3(x,lo,hi) == sorted-insert shift
      a3 = __builtin_amdgcn_fmed3f(d0, a2, a3);
      a2 = __builtin_amdgcn_fmed3f(d0, a1, a2);
      a1 = __builtin_amdgcn_fmed3f(d0, a0, a1);
      a0 = fminf(d0, a0);
      // chain G <- odd candidate
      g3 = __builtin_amdgcn_fmed3f(d1, g2, g3);
      g2 = __builtin_amdgcn_fmed3f(d1, g1, g2);
      g1 = __builtin_amdgcn_fmed3f(d1, g0, g1);
      g0 = fminf(d1, g0);
      float tau = fmaxf(a3, g3);               // >= running 8th >= final T8
      mm |= (uint32_t)(d0 <= tau) << jj;
      mm |= (uint32_t)(d1 <= tau) << (jj + 1);
    }
    // finalize this segment's survivors (ascending j, strict <)
    while (mm) {
      int bit = __builtin_ctz(mm); mm &= mm - 1;
      int j = base + bit;
      float dd = d2f(px, py, pz, sp, srefw[j]);
      insert8(dd, j, dist, id);
    }
  }

  uint16_t* pp = part + ((size_t)P * NCH + ch) * 8;
  #pragma unroll
  for (int k = 0; k < 8; ++k)
    pp[k] = (uint16_t)((rbase + id[k]) & (NRr - 1));
}

// ------- attention + fused merge: one wave per pred point -------------------
// Merge: 128 part candidates = 64 u32 (1/lane, coalesced). Each lane: exact
// d2f of its 2 cands (parallel gathers), key = fkey(d2)<<32 | j (monotone,
// lex (d2,j)). 8 rounds of butterfly u64-min + winner masking == insert_lex
// lex top-8 exactly (all j distinct: disjoint chunk ranges).
__global__ __launch_bounds__(256) void k_attn(const float* __restrict__ feat_q,
    const float* __restrict__ feat_k, const float* __restrict__ feat_v,
    const uint16_t* __restrict__ part, const float* __restrict__ xyz_pred,
    const float4* __restrict__ ref4, uint16_t* __restrict__ g) {
  int wave = threadIdx.x >> 6;
  int lane = threadIdx.x & 63;
  int P = blockIdx.x * 4 + wave;     // 0..16383
  int b = P >> 13;

  // ---- fused merge ----
  float px = xyz_pred[P*3+0];
  float py = xyz_pred[P*3+1];
  float pz = xyz_pred[P*3+2];
  float sp = __fadd_rn(__fadd_rn(__fmul_rn(px,px), __fmul_rn(py,py)), __fmul_rn(pz,pz));
  const float4* refbase = ref4 + (size_t)b * NRr;

  const uint32_t* pw = (const uint32_t*)(part + (size_t)P * (NCH * 8));
  uint32_t two = pw[lane];                 // cands 2*lane (lo u16), 2*lane+1 (hi)
  int j0 = two & (NRr - 1);
  int j1 = (two >> 16) & (NRr - 1);
  float d0 = d2f(px, py, pz, sp, refbase[j0]);
  float d1 = d2f(px, py, pz, sp, refbase[j1]);
  uint64_t k0 = ((uint64_t)fkey(d0) << 32) | (uint32_t)j0;
  uint64_t k1 = ((uint64_t)fkey(d1) << 32) | (uint32_t)j1;

  int nb[8];
  #pragma unroll
  for (int r = 0; r < 8; ++r) {
    uint64_t m = (k0 < k1) ? k0 : k1;
    #pragma unroll
    for (int s = 1; s < 64; s <<= 1) {
      uint64_t o = __shfl_xor(m, s, 64);
      m = (o < m) ? o : m;
    }
    nb[r] = (int)(uint32_t)(m & 0xFFFFFFFFu) & (NRr - 1);
    if (k0 == m) k0 = ~0ULL;
    if (k1 == m) k1 = ~0ULL;
  }

  // ---- attention (unchanged) ----
  float4 qv = *(const float4*)(feat_q + (size_t)P*NC + lane*4);
  const float* kb = feat_k + (size_t)b * NRr * NC;
  const float* vb = feat_v + (size_t)b * NRr * NC;

  float s[8];
  #pragma unroll
  for (int k = 0; k < 8; ++k) {
    float4 kv = *(const float4*)(kb + (size_t)nb[k]*NC + lane*4);
    float p = qv.x * kv.x;
    p = fmaf(qv.y, kv.y, p);
    p = fmaf(qv.z, kv.z, p);
    p = fmaf(qv.w, kv.w, p);
    s[k] = p;
  }
  #pragma unroll
  for (int k = 0; k < 8; ++k) {
    float v = s[k];
    #pragma unroll
    for (int m = 1; m < 64; m <<= 1) v += __shfl_xor(v, m, 64);
    s[k] = v * 0.0625f;   // / sqrt(256), exact
  }
  float mx = s[0];
  #pragma unroll
  for (int k = 1; k < 8; ++k) mx = fmaxf(mx, s[k]);
  float e[8], sum = 0.f;
  #pragma unroll
  for (int k = 0; k < 8; ++k) { e[k] = expf(s[k] - mx); sum += e[k]; }
  float inv = 1.0f / sum;

  float g0 = 0.f, g1 = 0.f, g2 = 0.f, g3 = 0.f;
  #pragma unroll
  for (int k = 0; k < 8; ++k) {
    float4 vv = *(const float4*)(vb + (size_t)nb[k]*NC + lane*4);
    float w = e[k] * inv;
    g0 = fmaf(w, vv.x, g0);
    g1 = fmaf(w, vv.y, g1);
    g2 = fmaf(w, vv.z, g2);
    g3 = fmaf(w, vv.w, g3);
  }
  uint32_t p0 = ((uint32_t)f2bf(g1) << 16) | f2bf(g0);
  uint32_t p1 = ((uint32_t)f2bf(g3) << 16) | f2bf(g2);
  *(uint2*)(g + (size_t)P*NC + lane*4) = make_uint2(p0, p1);
}

// ---------------- zero-fill ref halves of output (runs LAST) ----------------
__global__ void k_zero(float4* __restrict__ o) {
  int i = blockIdx.x * 256 + threadIdx.x;  // 0 .. 2097151
  int b = i >> 20;                         // region 0 or 1
  int r = i & 1048575;                     // 1M float4 per 16MB region
  o[(size_t)b * 2097152 + r] = make_float4(0.f, 0.f, 0.f, 0.f);
}

// ---------------- final GEMM: g[16384,256]bf16 @ A^T + bbig -> f32 ----------
__global__ __launch_bounds__(256) void k_gemm(const uint16_t* __restrict__ g,
    const uint16_t* __restrict__ Aw, const float* __restrict__ bbig,
    float* __restrict__ outp) {
  // LDS stride 136 (272B): 16B-aligned rows, 4-bank shift/row => conflict-free
  __shared__ __align__(16) uint16_t sA[64 * 136];
  __shared__ __align__(16) uint16_t sB[64 * 136];
  int t = threadIdx.x;
  int lane = t & 63, wave = t >> 6;
  int wm = (wave >> 1) * 32, wn = (wave & 1) * 32;
  int q = lane >> 4, rr = lane & 15;
  int bm = blockIdx.x;   // 0..255 (M tiles of 64)
  int bn = blockIdx.y;   // 0..7   (N tiles of 64)
  f32x4 zero = {0.f, 0.f, 0.f, 0.f};
  f32x4 acc[2][2] = {{zero, zero}, {zero, zero}};

  for (int ph = 0; ph < 2; ++ph) {      // K = 256 in two 128 phases
    #pragma unroll
    for (int i = 0; i < 4; ++i) {
      int cc  = t + i * 256;            // 0..1023 chunks of 8 bf16
      int row = cc >> 4;                // 16 chunks per row
      int col = (cc & 15) << 3;
      uint4 da = *(const uint4*)(g  + ((size_t)(bm*64 + row))*NC + ph*128 + col);
      *(uint4*)(&sA[row*136 + col]) = da;
      uint4 db = *(const uint4*)(Aw + ((size_t)(bn*64 + row))*NC + ph*128 + col);
      *(uint4*)(&sB[row*136 + col]) = db;
    }
    __syncthreads();
    #pragma unroll
    for (int kk = 0; kk < 4; ++kk) {
      int ko = kk*32 + q*8;
      bf16x8 a0 = *(const bf16x8*)(&sA[(wm      + rr)*136 + ko]);
      bf16x8 a1 = *(const bf16x8*)(&sA[(wm + 16 + rr)*136 + ko]);
      bf16x8 b0 = *(const bf16x8*)(&sB[(wn      + rr)*136 + ko]);
      bf16x8 b1 = *(const bf16x8*)(&sB[(wn + 16 + rr)*136 + ko]);
      acc[0][0] = __builtin_amdgcn_mfma_f32_16x16x32_bf16(a0, b0, acc[0][0], 0, 0, 0);
      acc[0][1] = __builtin_amdgcn_mfma_f32_16x16x32_bf16(a0, b1, acc[0][1], 0, 0, 0);
      acc[1][0] = __builtin_amdgcn_mfma_f32_16x16x32_bf16(a1, b0, acc[1][0], 0, 0, 0);
      acc[1][1] = __builtin_amdgcn_mfma_f32_16x16x32_bf16(a1, b1, acc[1][1], 0, 0, 0);
    }
    __syncthreads();
  }
  #pragma unroll
  for (int j = 0; j < 2; ++j) {
    int col = bn*64 + wn + j*16 + rr;
    float bias = bbig[col];
    #pragma unroll
    for (int i = 0; i < 2; ++i) {
      #pragma unroll
      for (int r = 0; r < 4; ++r) {
        int row = bm*64 + wm + i*16 + q*4 + r;   // C/D: col=lane&15, row=(lane>>4)*4+reg
        float v = acc[i][j][r] + bias;
        int bb = row >> 13, p = row & 8191;
        outp[((size_t)(bb*16384 + 8192 + p))*512 + col] = v;
      }
    }
  }
}

extern "C" void kernel_launch(void* const* d_in, const int* in_sizes, int n_in,
                              void* d_out, int out_size, void* d_ws, size_t ws_size,
                              hipStream_t stream) {
  const float* xyz_ref  = (const float*)d_in[0];
  const float* xyz_pred = (const float*)d_in[1];
  const float* feat_k   = (const float*)d_in[2];
  const float* feat_q   = (const float*)d_in[3];
  const float* feat_v   = (const float*)d_in[4];
  const float* Wv       = (const float*)d_in[5];
  const float* bv       = (const float*)d_in[6];
  const float* Wo       = (const float*)d_in[7];
  const float* bo       = (const float*)d_in[8];
  const float* Wout     = (const float*)d_in[9];
  float* outp = (float*)d_out;

  // ALL scratch inside d_out's dead ref-half regions (f32 output, 64MB):
  char* ob = (char*)d_out;
  uint16_t* g    = (uint16_t*)ob;                    // [0, 8M)    bf16 16384x256
  float4*   ref4 = (float4*)(ob + 8388608);          // [8M, 8.25M)
  uint16_t* Aw   = (uint16_t*)(ob + 9175040);        // [8.75M, 9M)
  float*    bbig = (float*)(ob + 9437184);           // [9M, +2K)
  uint16_t* part = (uint16_t*)(ob + 33554432);       // [32M, 36M)  4 MB u16

  k_prep   <<<256,  64,  0, stream>>>(xyz_ref, ref4);
  k_knn    <<<1088, 256, 0, stream>>>(xyz_pred, ref4, part,
                                      Wv, bv, Wo, bo, Wout, Aw, bbig);
  k_attn   <<<4096, 256, 0, stream>>>(feat_q, feat_k, feat_v, part,
                                      xyz_pred, ref4, g);
  k_gemm   <<<dim3(256, 8), 256, 0, stream>>>(g, Aw, bbig, outp);
  k_zero   <<<8192, 256, 0, stream>>>((float4*)outp);
}